// Round 9
// baseline (175.376 us; speedup 1.0000x reference)
//
#include <hip/hip_runtime.h>
#include <math.h>

// Problem constants: B=2, L=1024, D=512, H=8, h=64, K=H=8, EPS=1e-5
// Layouts: q/kc/vc stored as [B*H][L][64] (bh*65536 + l*64 + d)
// UB2: bf16 conv inputs, d-major [tensor][bh][d=64][l=1024]
// TB:  bf16 Toeplitz filters [h=8][t=1024][s=1024], zero above diagonal

typedef __attribute__((ext_vector_type(8))) short short8;
typedef __attribute__((ext_vector_type(4))) float floatx4;

__device__ __forceinline__ unsigned short f2bf(float f) {
    unsigned int u = __float_as_uint(f);
    unsigned int r = (u + 0x7FFFu + ((u >> 16) & 1u)) >> 16;   // RNE
    return (unsigned short)r;
}

// ---------------------------------------------------------------------------
// K0: fused prep.  blocks 0-511: cast x -> bf16.  512-767: transpose+cast
// weights.  768-1023: materialize Toeplitz filters TB[h][t][s].
// ---------------------------------------------------------------------------
__global__ __launch_bounds__(256) void k_prep(
    const float* __restrict__ x,
    const float* __restrict__ wq, const float* __restrict__ wk,
    const float* __restrict__ wv, const float* __restrict__ wo,
    const float* __restrict__ sb,
    unsigned short* __restrict__ xb,
    unsigned short* __restrict__ wT, unsigned short* __restrict__ woT,
    unsigned short* __restrict__ TB)
{
    __shared__ float sf[64][65];
    const int blk = blockIdx.x;
    const int tid = threadIdx.x;

    if (blk < 512) {                       // ---- castx ----
        const int gid = blk * 256 + tid;
        const float4* x4 = (const float4*)x;
        float4 a = x4[gid*2], b = x4[gid*2+1];
        uint4 o;
        o.x = f2bf(a.x) | ((unsigned)f2bf(a.y) << 16);
        o.y = f2bf(a.z) | ((unsigned)f2bf(a.w) << 16);
        o.z = f2bf(b.x) | ((unsigned)f2bf(b.y) << 16);
        o.w = f2bf(b.z) | ((unsigned)f2bf(b.w) << 16);
        ((uint4*)xb)[gid] = o;
    } else if (blk < 768) {                // ---- packw ----
        const int t = blk - 512;
        const float* src; unsigned short* dst; int n0, c0, k0;
        if (t < 192) {
            int nt = t >> 3, kt = t & 7;
            n0 = nt * 64; k0 = kt * 64;
            int z = n0 >> 9; c0 = n0 & 511;
            src = (z == 0) ? wq : (z == 1) ? wk : wv;
            dst = wT;
        } else {
            int u = t - 192; int nt = u >> 3, kt = u & 7;
            n0 = nt * 64; c0 = n0; k0 = kt * 64;
            src = wo; dst = woT;
        }
        const int rr = tid >> 4, c4 = tid & 15;
        #pragma unroll
        for (int g = 0; g < 4; ++g) {
            int r = g*16 + rr;
            float4 v = *(const float4*)&src[(size_t)(k0 + r)*512 + c0 + c4*4];
            sf[r][c4*4+0]=v.x; sf[r][c4*4+1]=v.y; sf[r][c4*4+2]=v.z; sf[r][c4*4+3]=v.w;
        }
        __syncthreads();
        #pragma unroll
        for (int g = 0; g < 4; ++g) {
            int c = g*16 + rr;
            int kk = c4*4;
            ushort4 o;
            o.x = f2bf(sf[kk+0][c]); o.y = f2bf(sf[kk+1][c]);
            o.z = f2bf(sf[kk+2][c]); o.w = f2bf(sf[kk+3][c]);
            *(ushort4*)&dst[(size_t)(n0 + c)*512 + k0 + kk] = o;
        }
    } else {                               // ---- mkT ----
        const int u = blk - 768;
        const int h = u >> 5;
        const int r0 = (u & 31) * 32;
        unsigned short* sbc = (unsigned short*)sf;     // 1024 ushorts
        for (int i = tid; i < 1024; i += 256)
            sbc[i] = f2bf(sb[i*8 + h]);
        __syncthreads();
        const int rr = tid >> 3, c0 = (tid & 7) * 128;
        const int t = r0 + rr;
        unsigned short* row = TB + ((size_t)h * 1024 + t) * 1024;
        for (int c = c0; c < c0 + 128; c += 8) {
            unsigned short v[8];
            #pragma unroll
            for (int j = 0; j < 8; ++j) {
                int s = c + j;
                v[j] = (t >= s) ? sbc[t - s] : (unsigned short)0;
            }
            uint4 o;
            o.x = v[0] | ((unsigned)v[1]<<16);
            o.y = v[2] | ((unsigned)v[3]<<16);
            o.z = v[4] | ((unsigned)v[5]<<16);
            o.w = v[6] | ((unsigned)v[7]<<16);
            *(uint4*)&row[c] = o;
        }
    }
}

// ---------------------------------------------------------------------------
// K1: QKV projection via MFMA.  C[2048][1536] = xb @ wT^T.  q -> fp32 [bh][l][64];
// k (scaled), v -> bf16 d-major UB2.  grid (12, 16), 256 thr.
// ---------------------------------------------------------------------------
__global__ __launch_bounds__(256) void k_qkv_mfma(
    const unsigned short* __restrict__ xb, const unsigned short* __restrict__ wT,
    const float* __restrict__ bq, const float* __restrict__ bk,
    const float* __restrict__ bv,
    float* __restrict__ qo, unsigned short* __restrict__ ub2)
{
    const int tid = threadIdx.x;
    const int lane = tid & 63, wave = tid >> 6;
    const int q = lane >> 4, ln = lane & 15;
    const int wm = (wave >> 1) * 64, wn = (wave & 1) * 64;
    const int m0 = blockIdx.y * 128;
    const int n0 = blockIdx.x * 128;

    __shared__ unsigned short As[128*40];
    __shared__ unsigned short Bs[128*40];

    floatx4 acc[4][4];
    #pragma unroll
    for (int i = 0; i < 4; ++i)
        #pragma unroll
        for (int j = 0; j < 4; ++j)
            acc[i][j] = (floatx4){0.f, 0.f, 0.f, 0.f};

    const uint4* Ag = (const uint4*)xb;
    const uint4* Bg = (const uint4*)wT;
    for (int k0 = 0; k0 < 512; k0 += 32) {
        #pragma unroll
        for (int s = 0; s < 2; ++s) {
            int c = tid*2 + s;
            int r = c >> 2, cp = c & 3;
            uint4 va = Ag[(size_t)(m0 + r)*64 + (k0 >> 3) + cp];
            uint4 vb = Bg[(size_t)(n0 + r)*64 + (k0 >> 3) + cp];
            *(uint4*)&As[r*40 + cp*8] = va;
            *(uint4*)&Bs[r*40 + cp*8] = vb;
        }
        __syncthreads();
        short8 af[4], bfr[4];
        #pragma unroll
        for (int i = 0; i < 4; ++i) {
            af[i]  = *(const short8*)&As[(wm + i*16 + ln)*40 + q*8];
            bfr[i] = *(const short8*)&Bs[(wn + i*16 + ln)*40 + q*8];
        }
        #pragma unroll
        for (int mi = 0; mi < 4; ++mi)
            #pragma unroll
            for (int ni = 0; ni < 4; ++ni)
                acc[mi][ni] = __builtin_amdgcn_mfma_f32_16x16x32_bf16(
                    af[mi], bfr[ni], acc[mi][ni], 0, 0, 0);
        __syncthreads();
    }

    const int z = n0 >> 9;
    if (z == 0) {
        #pragma unroll
        for (int mi = 0; mi < 4; ++mi) {
            #pragma unroll
            for (int ni = 0; ni < 4; ++ni) {
                int gcol = n0 + wn + ni*16 + ln;
                int c = gcol & 511;
                int head = c >> 6, dd = c & 63;
                float bb = bq[c];
                #pragma unroll
                for (int reg = 0; reg < 4; ++reg) {
                    int row = m0 + wm + mi*16 + q*4 + reg;
                    int b = row >> 10, l = row & 1023;
                    qo[(size_t)((b*8 + head)*1024 + l)*64 + dd] =
                        acc[mi][ni][reg] + bb;
                }
            }
        }
    } else {
        const float scale = (z == 1) ? 0.125f : 1.0f;
        const float* bias = (z == 1) ? bk : bv;
        unsigned short* dst = ub2 + (size_t)(z-1) * 16 * 64 * 1024;
        #pragma unroll
        for (int mi = 0; mi < 4; ++mi) {
            #pragma unroll
            for (int ni = 0; ni < 4; ++ni) {
                int gcol = n0 + wn + ni*16 + ln;
                int c = gcol & 511;
                int head = c >> 6, dd = c & 63;
                float bb = bias[c];
                int row0 = m0 + wm + mi*16 + q*4;
                int b = row0 >> 10, l0 = row0 & 1023;
                ushort4 o;
                o.x = f2bf((acc[mi][ni][0] + bb) * scale);
                o.y = f2bf((acc[mi][ni][1] + bb) * scale);
                o.z = f2bf((acc[mi][ni][2] + bb) * scale);
                o.w = f2bf((acc[mi][ni][3] + bb) * scale);
                *(ushort4*)&dst[((size_t)((b*8 + head)*64) + dd)*1024 + l0] = o;
            }
        }
    }
}

// ---------------------------------------------------------------------------
// K2: conv (both tensors) as Toeplitz GEMM + inline gate logits.
// grid (16 tTiles, 16 bh), 256 thr = 4 waves.  A-tile (TB rows) staged once,
// reused for k and v (8 MFMA/step).  Epilogue: KC/VC to global + fp32 LDS,
// then gate logit per row = v . (Wg k) in fp32 (Wg via LDS broadcast),
// relu^2 + eps -> GL.  1 block/CU so the 67 KB LDS costs no occupancy.
// ---------------------------------------------------------------------------
__global__ __launch_bounds__(256) void k_convgate(
    const unsigned short* __restrict__ TB,
    const unsigned short* __restrict__ ub2,
    const float* __restrict__ wg_w, const float* __restrict__ wg_b,
    float* __restrict__ kc, float* __restrict__ vc, float* __restrict__ gl)
{
    const int tid = threadIdx.x;
    const int lane = tid & 63, wave = tid >> 6;
    const int q = lane >> 4, ln = lane & 15;
    const int it = blockIdx.x, t0 = it * 64;
    const int bh = blockIdx.y, h = bh & 7;

    __shared__ unsigned short As[64*40];
    __shared__ unsigned short Bks[64*40];
    __shared__ unsigned short Bvs[64*40];
    __shared__ float wgs[4096];            // Wg [m][n] row-major (broadcast reads)
    __shared__ float kvt[2][64][68];       // fp32 conv tiles (k, v)
    __shared__ float red[64][4];

    for (int i = tid; i < 1024; i += 256)
        ((float4*)wgs)[i] = ((const float4*)wg_w)[i];

    const uint4* Ag = (const uint4*)TB;    // 128 uint4 per 1024-elem row
    const uint4* Bg = (const uint4*)ub2;
    const size_t abase  = (size_t)h * 131072 + (size_t)t0 * 128;
    const size_t bkbase = (size_t)bh * 8192;
    const size_t bvbase = (size_t)(16 + bh) * 8192;

    floatx4 acck[4], accv[4];
    #pragma unroll
    for (int i = 0; i < 4; ++i) {
        acck[i] = (floatx4){0.f,0.f,0.f,0.f};
        accv[i] = (floatx4){0.f,0.f,0.f,0.f};
    }

    const int kend = t0 + 64;
    const int r = tid >> 2, cp = tid & 3;
    for (int k0 = 0; k0 < kend; k0 += 32) {
        uint4 va = Ag[abase  + (size_t)r*128 + (k0 >> 3) + cp];
        uint4 vk = Bg[bkbase + (size_t)r*128 + (k0 >> 3) + cp];
        uint4 vv = Bg[bvbase + (size_t)r*128 + (k0 >> 3) + cp];
        *(uint4*)&As[r*40 + cp*8]  = va;
        *(uint4*)&Bks[r*40 + cp*8] = vk;
        *(uint4*)&Bvs[r*40 + cp*8] = vv;
        __syncthreads();
        short8 a = *(const short8*)&As[(wave*16 + ln)*40 + q*8];
        #pragma unroll
        for (int ni = 0; ni < 4; ++ni) {
            short8 bk8 = *(const short8*)&Bks[(ni*16 + ln)*40 + q*8];
            short8 bv8 = *(const short8*)&Bvs[(ni*16 + ln)*40 + q*8];
            acck[ni] = __builtin_amdgcn_mfma_f32_16x16x32_bf16(a, bk8, acck[ni], 0, 0, 0);
            accv[ni] = __builtin_amdgcn_mfma_f32_16x16x32_bf16(a, bv8, accv[ni], 0, 0, 0);
        }
        __syncthreads();
    }

    float* dks = kc + (size_t)bh * 65536;
    float* dvs = vc + (size_t)bh * 65536;
    #pragma unroll
    for (int ni = 0; ni < 4; ++ni)
        #pragma unroll
        for (int reg = 0; reg < 4; ++reg) {
            int row = wave*16 + q*4 + reg;         // local row 0..63
            float kvv = acck[ni][reg];
            float vvv = accv[ni][reg];
            dks[(size_t)(t0 + row)*64 + ni*16 + ln] = kvv;
            dvs[(size_t)(t0 + row)*64 + ni*16 + ln] = vvv;
            kvt[0][row][ni*16 + ln] = kvv;
            kvt[1][row][ni*16 + ln] = vvv;
        }
    __syncthreads();

    // gate: row = tid>>2, team = tid&3 handles m in [team*16, team*16+16)
    {
        const int row = tid >> 2, team = tid & 3;
        float4 kreg[16];
        #pragma unroll
        for (int c = 0; c < 16; ++c)
            kreg[c] = *(const float4*)&kvt[0][row][c*4];
        float partial = 0.0f;
        #pragma unroll
        for (int mm = 0; mm < 16; ++mm) {
            int m = team*16 + mm;
            float vv = kvt[1][row][m];
            float dot = 0.0f;
            #pragma unroll
            for (int c = 0; c < 16; ++c) {
                float4 w4 = *(const float4*)&wgs[m*64 + c*4];   // broadcast
                dot += w4.x*kreg[c].x + w4.y*kreg[c].y
                     + w4.z*kreg[c].z + w4.w*kreg[c].w;
            }
            partial += vv * dot;
        }
        red[row][team] = partial;
    }
    __syncthreads();
    if (tid < 64) {
        float4 r4 = *(const float4*)&red[tid][0];
        float s = r4.x + r4.y + r4.z + r4.w + wg_b[0];
        float rr = fmaxf(s, 0.0f);
        gl[bh*1024 + t0 + tid] = rr*rr + 1e-5f;
    }
}

// ---------------------------------------------------------------------------
// K3: A_part[slc][bh] = sum_{j in slice} w_j * outer(v_conv[j], k_conv[j]),
// with the gate scan (w_j = g_j * suffix(1/prefix(g))) computed inline.
// grid (16 bh, 4 slices), 256 thr.
// ---------------------------------------------------------------------------
__global__ __launch_bounds__(256) void k_amat(
    const float* __restrict__ kc, const float* __restrict__ vc,
    const float* __restrict__ gl, float* __restrict__ apart)
{
    const int tid = threadIdx.x, tx = tid & 15, ty = tid >> 4;
    const int bh = blockIdx.x, slc = blockIdx.y;
    const float* kb = kc + (size_t)bh * 65536;
    const float* vb = vc + (size_t)bh * 65536;

    __shared__ float sbuf[256];
    __shared__ float wfull[1024];
    __shared__ __align__(16) float vs[16][68];
    __shared__ __align__(16) float ks2[16][68];

    {
        const float4 g4 = ((const float4*)(gl + bh*1024))[tid];
        float g[4] = {g4.x, g4.y, g4.z, g4.w};
        float p[4];
        p[0]=g[0]; p[1]=p[0]+g[1]; p[2]=p[1]+g[2]; p[3]=p[2]+g[3];
        const float s = p[3];
        sbuf[tid] = s;
        __syncthreads();
        for (int off = 1; off < 256; off <<= 1) {
            float t = (tid >= off) ? sbuf[tid-off] : 0.0f;
            __syncthreads();
            sbuf[tid] += t;
            __syncthreads();
        }
        const float base = sbuf[tid] - s;
        float r[4], pr[4];
        #pragma unroll
        for (int u = 0; u < 4; ++u) r[u] = 1.0f / (base + p[u] + 1e-5f);
        pr[0]=r[0]; pr[1]=pr[0]+r[1]; pr[2]=pr[1]+r[2]; pr[3]=pr[2]+r[3];
        const float sr = pr[3];
        __syncthreads();
        sbuf[tid] = sr;
        __syncthreads();
        for (int off = 1; off < 256; off <<= 1) {
            float t = (tid >= off) ? sbuf[tid-off] : 0.0f;
            __syncthreads();
            sbuf[tid] += t;
            __syncthreads();
        }
        const float Rtot  = sbuf[255];
        const float baser = sbuf[tid] - sr;
        wfull[tid*4+0] = g[0] * (Rtot - (baser + pr[0]) + r[0]);
        wfull[tid*4+1] = g[1] * (Rtot - (baser + pr[1]) + r[1]);
        wfull[tid*4+2] = g[2] * (Rtot - (baser + pr[2]) + r[2]);
        wfull[tid*4+3] = g[3] * (Rtot - (baser + pr[3]) + r[3]);
    }
    __syncthreads();

    float acc[4][4] = {};
    const float4* k4 = (const float4*)kb;
    const float4* v4 = (const float4*)vb;
    for (int j0 = slc*256; j0 < slc*256 + 256; j0 += 16) {
        {
            int r = tid >> 4, c4 = tid & 15;
            *(float4*)&vs[r][c4*4]  = v4[(size_t)(j0 + r)*16 + c4];
            *(float4*)&ks2[r][c4*4] = k4[(size_t)(j0 + r)*16 + c4];
        }
        __syncthreads();
        #pragma unroll
        for (int jj = 0; jj < 16; ++jj) {
            float wj = wfull[j0 + jj];
            float a[4];
            a[0] = vs[jj][ty*4+0]*wj; a[1] = vs[jj][ty*4+1]*wj;
            a[2] = vs[jj][ty*4+2]*wj; a[3] = vs[jj][ty*4+3]*wj;
            float4 b4 = *(const float4*)&ks2[jj][tx*4];
            float bb[4] = {b4.x, b4.y, b4.z, b4.w};
            #pragma unroll
            for (int ii = 0; ii < 4; ++ii)
                #pragma unroll
                for (int jc = 0; jc < 4; ++jc)
                    acc[ii][jc] += a[ii] * bb[jc];
        }
        __syncthreads();
    }
    float* ap = apart + (size_t)(slc*16 + bh) * 4096;
    #pragma unroll
    for (int i = 0; i < 4; ++i) {
        float4 o = { acc[i][0], acc[i][1], acc[i][2], acc[i][3] };
        *(float4*)&ap[(ty*4+i)*64 + tx*4] = o;
    }
}

// ---------------------------------------------------------------------------
// K4: ctxt = q @ A (summing the 4 A-partials on load), row-normalize,
// write unit vectors as bf16 into [B,L,D] layout.  grid (16, 16), 256 thr.
// ---------------------------------------------------------------------------
__global__ __launch_bounds__(256) void k_ctxt(
    const float* __restrict__ q, const float* __restrict__ apart,
    unsigned short* __restrict__ ub)
{
    const int tid = threadIdx.x, tx = tid & 15, ty = tid >> 4;
    const int l0 = blockIdx.x * 64;
    const int bh = blockIdx.y;
    const float* qb = q + (size_t)bh * 65536;

    __shared__ float qs[64][17];
    __shared__ __align__(16) float As[16][68];
    float acc[4][4] = {};
    const float4* q4 = (const float4*)qb;
    const float4* a4 = (const float4*)apart;
    for (int d0 = 0; d0 < 64; d0 += 16) {
        {
            int r = tid >> 2, c4 = tid & 3;
            float4 t = q4[(size_t)(l0 + r)*16 + (d0 >> 2) + c4];
            qs[r][c4*4+0]=t.x; qs[r][c4*4+1]=t.y; qs[r][c4*4+2]=t.z; qs[r][c4*4+3]=t.w;
        }
        {
            int r = tid >> 4, c4 = tid & 15;
            size_t o = (size_t)(d0 + r)*16 + c4;
            float4 t0 = a4[(size_t)(0*16 + bh)*1024 + o];
            float4 t1 = a4[(size_t)(1*16 + bh)*1024 + o];
            float4 t2 = a4[(size_t)(2*16 + bh)*1024 + o];
            float4 t3 = a4[(size_t)(3*16 + bh)*1024 + o];
            float4 t;
            t.x = t0.x+t1.x+t2.x+t3.x; t.y = t0.y+t1.y+t2.y+t3.y;
            t.z = t0.z+t1.z+t2.z+t3.z; t.w = t0.w+t1.w+t2.w+t3.w;
            *(float4*)&As[r][c4*4] = t;
        }
        __syncthreads();
        #pragma unroll
        for (int dd = 0; dd < 16; ++dd) {
            float a[4];
            a[0] = qs[ty*4+0][dd]; a[1] = qs[ty*4+1][dd];
            a[2] = qs[ty*4+2][dd]; a[3] = qs[ty*4+3][dd];
            float4 b4 = *(const float4*)&As[dd][tx*4];
            float bb[4] = {b4.x, b4.y, b4.z, b4.w};
            #pragma unroll
            for (int ii = 0; ii < 4; ++ii)
                #pragma unroll
                for (int jj = 0; jj < 4; ++jj)
                    acc[ii][jj] += a[ii] * bb[jj];
        }
        __syncthreads();
    }
    __shared__ float red[64][17];
    __shared__ float nrm[64];
    #pragma unroll
    for (int i = 0; i < 4; ++i) {
        red[ty*4+i][tx] = acc[i][0]*acc[i][0] + acc[i][1]*acc[i][1]
                        + acc[i][2]*acc[i][2] + acc[i][3]*acc[i][3];
    }
    __syncthreads();
    if (tid < 64) {
        float s = 0.0f;
        #pragma unroll
        for (int t = 0; t < 16; ++t) s += red[tid][t];
        nrm[tid] = fmaxf(sqrtf(s), 1e-5f);
    }
    __syncthreads();
    const int b = bh >> 3, hd = bh & 7;
    #pragma unroll
    for (int i = 0; i < 4; ++i) {
        int lr = ty*4 + i;
        float inv = 1.0f / nrm[lr];
        ushort4 o;
        o.x = f2bf(acc[i][0]*inv); o.y = f2bf(acc[i][1]*inv);
        o.z = f2bf(acc[i][2]*inv); o.w = f2bf(acc[i][3]*inv);
        *(ushort4*)&ub[(size_t)(b*1024 + l0 + lr)*512 + hd*64 + tx*4] = o;
    }
}

// ---------------------------------------------------------------------------
// K5: out = Ub[2048][512](bf16) @ woT^T + wo_b via MFMA.  grid (4, 16).
// ---------------------------------------------------------------------------
__global__ __launch_bounds__(256) void k_out_mfma(
    const unsigned short* __restrict__ ub, const unsigned short* __restrict__ woT,
    const float* __restrict__ bo, float* __restrict__ out)
{
    const int tid = threadIdx.x;
    const int lane = tid & 63, wave = tid >> 6;
    const int q = lane >> 4, ln = lane & 15;
    const int wm = (wave >> 1) * 64, wn = (wave & 1) * 64;
    const int m0 = blockIdx.y * 128;
    const int n0 = blockIdx.x * 128;

    __shared__ unsigned short As[128*40];
    __shared__ unsigned short Bs[128*40];

    floatx4 acc[4][4];
    #pragma unroll
    for (int i = 0; i < 4; ++i)
        #pragma unroll
        for (int j = 0; j < 4; ++j)
            acc[i][j] = (floatx4){0.f, 0.f, 0.f, 0.f};

    const uint4* Ag = (const uint4*)ub;
    const uint4* Bg = (const uint4*)woT;
    for (int k0 = 0; k0 < 512; k0 += 32) {
        #pragma unroll
        for (int s = 0; s < 2; ++s) {
            int c = tid*2 + s;
            int r = c >> 2, cp = c & 3;
            uint4 va = Ag[(size_t)(m0 + r)*64 + (k0 >> 3) + cp];
            uint4 vb = Bg[(size_t)(n0 + r)*64 + (k0 >> 3) + cp];
            *(uint4*)&As[r*40 + cp*8] = va;
            *(uint4*)&Bs[r*40 + cp*8] = vb;
        }
        __syncthreads();
        short8 af[4], bfr[4];
        #pragma unroll
        for (int i = 0; i < 4; ++i) {
            af[i]  = *(const short8*)&As[(wm + i*16 + ln)*40 + q*8];
            bfr[i] = *(const short8*)&Bs[(wn + i*16 + ln)*40 + q*8];
        }
        #pragma unroll
        for (int mi = 0; mi < 4; ++mi)
            #pragma unroll
            for (int ni = 0; ni < 4; ++ni)
                acc[mi][ni] = __builtin_amdgcn_mfma_f32_16x16x32_bf16(
                    af[mi], bfr[ni], acc[mi][ni], 0, 0, 0);
        __syncthreads();
    }

    #pragma unroll
    for (int mi = 0; mi < 4; ++mi) {
        #pragma unroll
        for (int ni = 0; ni < 4; ++ni) {
            int gcol = n0 + wn + ni*16 + ln;
            float bb = bo[gcol];
            #pragma unroll
            for (int reg = 0; reg < 4; ++reg) {
                int row = m0 + wm + mi*16 + q*4 + reg;
                out[(size_t)row*512 + gcol] = acc[mi][ni][reg] + bb;
            }
        }
    }
}

extern "C" void kernel_launch(void* const* d_in, const int* in_sizes, int n_in,
                              void* d_out, int out_size, void* d_ws, size_t ws_size,
                              hipStream_t stream)
{
    const float* x   = (const float*)d_in[0];
    const float* sb  = (const float*)d_in[1];
    const float* wq  = (const float*)d_in[2];
    const float* bq  = (const float*)d_in[3];
    const float* wk  = (const float*)d_in[4];
    const float* bk  = (const float*)d_in[5];
    const float* wv  = (const float*)d_in[6];
    const float* bv  = (const float*)d_in[7];
    const float* wo  = (const float*)d_in[8];
    const float* bo  = (const float*)d_in[9];
    const float* wg  = (const float*)d_in[10];
    const float* wgb = (const float*)d_in[11];
    float* out = (float*)d_out;
    float* ws  = (float*)d_ws;

    // workspace layout (float offsets)
    float* Q   = ws;                        // 1048576  [B,H,L,64] fp32
    float* KC  = ws + 1048576;              // 1048576  k_conv fp32
    float* VC  = ws + 2*1048576;            // 1048576  v_conv fp32
    float* GL  = ws + 3*1048576;            // 16384
    float* AP  = GL + 16384;                // 262144
    float* fp  = AP + 262144;
    unsigned short* XB  = (unsigned short*)fp;              // 2048*512 bf16
    unsigned short* WT  = XB  + 1048576;                    // 1536*512 bf16
    unsigned short* WOT = WT  + 786432;                     // 512*512 bf16
    unsigned short* UB  = WOT + 262144;                     // 2048*512 bf16
    unsigned short* UB2 = UB  + 1048576;                    // 2*16*64*1024 bf16
    unsigned short* TB  = UB2 + 2097152;                    // 8*1024*1024 bf16

    k_prep     <<<dim3(1024),   256, 0, stream>>>(x, wq, wk, wv, wo, sb,
                                                  XB, WT, WOT, TB);
    k_qkv_mfma <<<dim3(12, 16), 256, 0, stream>>>(XB, WT, bq, bk, bv, Q, UB2);
    k_convgate <<<dim3(16, 16), 256, 0, stream>>>(TB, UB2, wg, wgb, KC, VC, GL);
    k_amat     <<<dim3(16, 4),  256, 0, stream>>>(KC, VC, GL, AP);
    k_ctxt     <<<dim3(16, 16), 256, 0, stream>>>(Q, AP, UB);
    k_out_mfma <<<dim3(4, 16),  256, 0, stream>>>(UB, WOT, bo, out);
}

// Round 10
// 164.276 us; speedup vs baseline: 1.0676x; 1.0676x over previous
//
#include <hip/hip_runtime.h>
#include <math.h>

// Problem constants: B=2, L=1024, D=512, H=8, h=64, K=H=8, EPS=1e-5
// Layouts: q/kc/vc stored as [B*H][L][64] (bh*65536 + l*64 + d)
// UB2: bf16 conv inputs, d-major [tensor][bh][d=64][l=1024]
// TB:  bf16 Toeplitz filters [h=8][t=1024][s=1024], zero above diagonal

typedef __attribute__((ext_vector_type(8))) short short8;
typedef __attribute__((ext_vector_type(4))) float floatx4;

__device__ __forceinline__ unsigned short f2bf(float f) {
    unsigned int u = __float_as_uint(f);
    unsigned int r = (u + 0x7FFFu + ((u >> 16) & 1u)) >> 16;   // RNE
    return (unsigned short)r;
}

// ---------------------------------------------------------------------------
// K0: fused prep.  blocks 0-511: cast x -> bf16.  512-767: transpose+cast
// weights.  768-1023: materialize Toeplitz filters TB[h][t][s].
// ---------------------------------------------------------------------------
__global__ __launch_bounds__(256) void k_prep(
    const float* __restrict__ x,
    const float* __restrict__ wq, const float* __restrict__ wk,
    const float* __restrict__ wv, const float* __restrict__ wo,
    const float* __restrict__ sb,
    unsigned short* __restrict__ xb,
    unsigned short* __restrict__ wT, unsigned short* __restrict__ woT,
    unsigned short* __restrict__ TB)
{
    __shared__ float sf[64][65];
    const int blk = blockIdx.x;
    const int tid = threadIdx.x;

    if (blk < 512) {                       // ---- castx ----
        const int gid = blk * 256 + tid;
        const float4* x4 = (const float4*)x;
        float4 a = x4[gid*2], b = x4[gid*2+1];
        uint4 o;
        o.x = f2bf(a.x) | ((unsigned)f2bf(a.y) << 16);
        o.y = f2bf(a.z) | ((unsigned)f2bf(a.w) << 16);
        o.z = f2bf(b.x) | ((unsigned)f2bf(b.y) << 16);
        o.w = f2bf(b.z) | ((unsigned)f2bf(b.w) << 16);
        ((uint4*)xb)[gid] = o;
    } else if (blk < 768) {                // ---- packw ----
        const int t = blk - 512;
        const float* src; unsigned short* dst; int n0, c0, k0;
        if (t < 192) {
            int nt = t >> 3, kt = t & 7;
            n0 = nt * 64; k0 = kt * 64;
            int z = n0 >> 9; c0 = n0 & 511;
            src = (z == 0) ? wq : (z == 1) ? wk : wv;
            dst = wT;
        } else {
            int u = t - 192; int nt = u >> 3, kt = u & 7;
            n0 = nt * 64; c0 = n0; k0 = kt * 64;
            src = wo; dst = woT;
        }
        const int rr = tid >> 4, c4 = tid & 15;
        #pragma unroll
        for (int g = 0; g < 4; ++g) {
            int r = g*16 + rr;
            float4 v = *(const float4*)&src[(size_t)(k0 + r)*512 + c0 + c4*4];
            sf[r][c4*4+0]=v.x; sf[r][c4*4+1]=v.y; sf[r][c4*4+2]=v.z; sf[r][c4*4+3]=v.w;
        }
        __syncthreads();
        #pragma unroll
        for (int g = 0; g < 4; ++g) {
            int c = g*16 + rr;
            int kk = c4*4;
            ushort4 o;
            o.x = f2bf(sf[kk+0][c]); o.y = f2bf(sf[kk+1][c]);
            o.z = f2bf(sf[kk+2][c]); o.w = f2bf(sf[kk+3][c]);
            *(ushort4*)&dst[(size_t)(n0 + c)*512 + k0 + kk] = o;
        }
    } else {                               // ---- mkT ----
        const int u = blk - 768;
        const int h = u >> 5;
        const int r0 = (u & 31) * 32;
        unsigned short* sbc = (unsigned short*)sf;     // 1024 ushorts
        for (int i = tid; i < 1024; i += 256)
            sbc[i] = f2bf(sb[i*8 + h]);
        __syncthreads();
        const int rr = tid >> 3, c0 = (tid & 7) * 128;
        const int t = r0 + rr;
        unsigned short* row = TB + ((size_t)h * 1024 + t) * 1024;
        for (int c = c0; c < c0 + 128; c += 8) {
            unsigned short v[8];
            #pragma unroll
            for (int j = 0; j < 8; ++j) {
                int s = c + j;
                v[j] = (t >= s) ? sbc[t - s] : (unsigned short)0;
            }
            uint4 o;
            o.x = v[0] | ((unsigned)v[1]<<16);
            o.y = v[2] | ((unsigned)v[3]<<16);
            o.z = v[4] | ((unsigned)v[5]<<16);
            o.w = v[6] | ((unsigned)v[7]<<16);
            *(uint4*)&row[c] = o;
        }
    }
}

// ---------------------------------------------------------------------------
// K1: QKV projection via MFMA, 128x64 tiles.  C[2048][1536] = xb @ wT^T.
// q -> fp32 [bh][l][64]; k (scaled), v -> bf16 d-major UB2.
// grid (24 nTiles, 16 mTiles) = 384 blocks, 256 thr = 4 waves; wave w owns
// rows [wm, wm+32) x all 64 cols (2x4 MFMA tiles).  Same K order as the
// 128x128 variant -> bit-identical outputs.
// ---------------------------------------------------------------------------
__global__ __launch_bounds__(256) void k_qkv_mfma(
    const unsigned short* __restrict__ xb, const unsigned short* __restrict__ wT,
    const float* __restrict__ bq, const float* __restrict__ bk,
    const float* __restrict__ bv,
    float* __restrict__ qo, unsigned short* __restrict__ ub2)
{
    const int tid = threadIdx.x;
    const int lane = tid & 63, wave = tid >> 6;
    const int q = lane >> 4, ln = lane & 15;
    const int wm = wave * 32;
    const int m0 = blockIdx.y * 128;
    const int n0 = blockIdx.x * 64;

    __shared__ unsigned short As[128*40];
    __shared__ unsigned short Bs[64*40];

    floatx4 acc[2][4];
    #pragma unroll
    for (int i = 0; i < 2; ++i)
        #pragma unroll
        for (int j = 0; j < 4; ++j)
            acc[i][j] = (floatx4){0.f, 0.f, 0.f, 0.f};

    const uint4* Ag = (const uint4*)xb;
    const uint4* Bg = (const uint4*)wT;
    for (int k0 = 0; k0 < 512; k0 += 32) {
        #pragma unroll
        for (int s = 0; s < 2; ++s) {
            int c = s*256 + tid;
            int r = c >> 2, cp = c & 3;
            uint4 va = Ag[(size_t)(m0 + r)*64 + (k0 >> 3) + cp];
            *(uint4*)&As[r*40 + cp*8] = va;
        }
        {
            int r = tid >> 2, cp = tid & 3;
            uint4 vb = Bg[(size_t)(n0 + r)*64 + (k0 >> 3) + cp];
            *(uint4*)&Bs[r*40 + cp*8] = vb;
        }
        __syncthreads();
        short8 af[2], bfr[4];
        #pragma unroll
        for (int i = 0; i < 2; ++i)
            af[i]  = *(const short8*)&As[(wm + i*16 + ln)*40 + q*8];
        #pragma unroll
        for (int i = 0; i < 4; ++i)
            bfr[i] = *(const short8*)&Bs[(i*16 + ln)*40 + q*8];
        #pragma unroll
        for (int mi = 0; mi < 2; ++mi)
            #pragma unroll
            for (int ni = 0; ni < 4; ++ni)
                acc[mi][ni] = __builtin_amdgcn_mfma_f32_16x16x32_bf16(
                    af[mi], bfr[ni], acc[mi][ni], 0, 0, 0);
        __syncthreads();
    }

    const int z = n0 >> 9;                 // 64-col block never straddles
    if (z == 0) {
        #pragma unroll
        for (int mi = 0; mi < 2; ++mi) {
            #pragma unroll
            for (int ni = 0; ni < 4; ++ni) {
                int c = (n0 + ni*16 + ln) & 511;
                int head = c >> 6, dd = c & 63;
                float bb = bq[c];
                #pragma unroll
                for (int reg = 0; reg < 4; ++reg) {
                    int row = m0 + wm + mi*16 + q*4 + reg;
                    int b = row >> 10, l = row & 1023;
                    qo[(size_t)((b*8 + head)*1024 + l)*64 + dd] =
                        acc[mi][ni][reg] + bb;
                }
            }
        }
    } else {
        const float scale = (z == 1) ? 0.125f : 1.0f;
        const float* bias = (z == 1) ? bk : bv;
        unsigned short* dst = ub2 + (size_t)(z-1) * 16 * 64 * 1024;
        #pragma unroll
        for (int mi = 0; mi < 2; ++mi) {
            #pragma unroll
            for (int ni = 0; ni < 4; ++ni) {
                int c = (n0 + ni*16 + ln) & 511;
                int head = c >> 6, dd = c & 63;
                float bb = bias[c];
                int row0 = m0 + wm + mi*16 + q*4;
                int b = row0 >> 10, l0 = row0 & 1023;
                ushort4 o;
                o.x = f2bf((acc[mi][ni][0] + bb) * scale);
                o.y = f2bf((acc[mi][ni][1] + bb) * scale);
                o.z = f2bf((acc[mi][ni][2] + bb) * scale);
                o.w = f2bf((acc[mi][ni][3] + bb) * scale);
                *(ushort4*)&dst[((size_t)((b*8 + head)*64) + dd)*1024 + l0] = o;
            }
        }
    }
}

// ---------------------------------------------------------------------------
// K2: conv as Toeplitz GEMM, LDS-staged (coalesced loads, ds_read_b128 frags).
// grid (32 bht, 16 tTiles), 256 thr = 4 waves.  Block: 64 t-rows x 64 d-cols.
// K-loop: k0 < t0+64, step 32 (upper triangle of TB is zero).
// ---------------------------------------------------------------------------
__global__ __launch_bounds__(256) void k_conv_mfma(
    const unsigned short* __restrict__ TB,
    const unsigned short* __restrict__ ub2,
    float* __restrict__ kc, float* __restrict__ vc)
{
    const int tid = threadIdx.x;
    const int lane = tid & 63, wave = tid >> 6;
    const int q = lane >> 4, ln = lane & 15;
    const int bht = blockIdx.x;
    const int it  = blockIdx.y;
    const int t0  = it * 64;
    const int bh  = bht & 15, h = bh & 7, tensor = bht >> 4;

    __shared__ unsigned short As[64*40];
    __shared__ unsigned short Bs[64*40];

    const uint4* Ag = (const uint4*)TB;    // 128 uint4 per 1024-elem row
    const uint4* Bg = (const uint4*)ub2;
    const size_t abase = (size_t)h * 131072 + (size_t)t0 * 128;
    const size_t bbase = (size_t)bht * 8192;

    floatx4 acc[4];
    #pragma unroll
    for (int i = 0; i < 4; ++i) acc[i] = (floatx4){0.f,0.f,0.f,0.f};

    const int kend = t0 + 64;
    const int r = tid >> 2, cp = tid & 3;
    for (int k0 = 0; k0 < kend; k0 += 32) {
        uint4 va = Ag[abase + (size_t)r*128 + (k0 >> 3) + cp];
        uint4 vb = Bg[bbase + (size_t)r*128 + (k0 >> 3) + cp];
        *(uint4*)&As[r*40 + cp*8] = va;
        *(uint4*)&Bs[r*40 + cp*8] = vb;
        __syncthreads();
        short8 a = *(const short8*)&As[(wave*16 + ln)*40 + q*8];
        short8 b0 = *(const short8*)&Bs[(0*16 + ln)*40 + q*8];
        short8 b1 = *(const short8*)&Bs[(1*16 + ln)*40 + q*8];
        short8 b2 = *(const short8*)&Bs[(2*16 + ln)*40 + q*8];
        short8 b3 = *(const short8*)&Bs[(3*16 + ln)*40 + q*8];
        acc[0] = __builtin_amdgcn_mfma_f32_16x16x32_bf16(a, b0, acc[0], 0, 0, 0);
        acc[1] = __builtin_amdgcn_mfma_f32_16x16x32_bf16(a, b1, acc[1], 0, 0, 0);
        acc[2] = __builtin_amdgcn_mfma_f32_16x16x32_bf16(a, b2, acc[2], 0, 0, 0);
        acc[3] = __builtin_amdgcn_mfma_f32_16x16x32_bf16(a, b3, acc[3], 0, 0, 0);
        __syncthreads();
    }

    float* dst = (tensor ? vc : kc) + (size_t)bh * 65536;
    #pragma unroll
    for (int ni = 0; ni < 4; ++ni)
        #pragma unroll
        for (int reg = 0; reg < 4; ++reg) {
            int row = t0 + wave*16 + q*4 + reg;
            dst[(size_t)row*64 + ni*16 + ln] = acc[ni][reg];
        }
}

// ---------------------------------------------------------------------------
// K3: gate values.  grid (16 lTiles, 16 bh), 256 thr.
// ---------------------------------------------------------------------------
__global__ __launch_bounds__(256) void k_gate(
    const float* __restrict__ kc, const float* __restrict__ vc,
    const float* __restrict__ wg_w, const float* __restrict__ wg_b,
    float* __restrict__ gl)
{
    const int tid = threadIdx.x, tx = tid & 15, ty = tid >> 4;
    const int l0 = blockIdx.x * 64;
    const int bh = blockIdx.y;
    const float* kb = kc + (size_t)bh * 65536;
    const float* vb = vc + (size_t)bh * 65536;

    __shared__ float ks[64][17];
    __shared__ __align__(16) float wsh[16][68];
    float acc[4][4] = {};
    const float4* k4 = (const float4*)kb;
    for (int n0 = 0; n0 < 64; n0 += 16) {
        {
            int r = tid >> 2, c4 = tid & 3;
            float4 t = k4[(size_t)(l0 + r) * 16 + (n0 >> 2) + c4];
            ks[r][c4*4+0]=t.x; ks[r][c4*4+1]=t.y; ks[r][c4*4+2]=t.z; ks[r][c4*4+3]=t.w;
        }
        for (int i = tid; i < 1024; i += 256) {
            int r = i >> 6, c = i & 63;
            wsh[r][c] = wg_w[c*64 + n0 + r];
        }
        __syncthreads();
        #pragma unroll
        for (int kk = 0; kk < 16; ++kk) {
            float a[4];
            a[0] = ks[ty*4+0][kk]; a[1] = ks[ty*4+1][kk];
            a[2] = ks[ty*4+2][kk]; a[3] = ks[ty*4+3][kk];
            float4 b4 = *(const float4*)&wsh[kk][tx*4];
            float bb[4] = {b4.x, b4.y, b4.z, b4.w};
            #pragma unroll
            for (int ii = 0; ii < 4; ++ii)
                #pragma unroll
                for (int jj = 0; jj < 4; ++jj)
                    acc[ii][jj] += a[ii] * bb[jj];
        }
        __syncthreads();
    }
    __shared__ float red[64][17];
    const float wgb = wg_b[0];
    const float4* v4p = (const float4*)vb;
    #pragma unroll
    for (int i = 0; i < 4; ++i) {
        int lr = ty*4 + i;
        float4 vv = v4p[(size_t)(l0 + lr) * 16 + tx];
        red[lr][tx] = acc[i][0]*vv.x + acc[i][1]*vv.y + acc[i][2]*vv.z + acc[i][3]*vv.w;
    }
    __syncthreads();
    if (tid < 64) {
        float s = 0.0f;
        #pragma unroll
        for (int t = 0; t < 16; ++t) s += red[tid][t];
        float logit = s + wgb;
        float r = fmaxf(logit, 0.0f);
        gl[bh*1024 + l0 + tid] = r*r + 1e-5f;
    }
}

// ---------------------------------------------------------------------------
// K4: A_part[slc][bh] = sum_{j in slice} w_j * outer(v_conv[j], k_conv[j]),
// with the gate scan (w_j = g_j * suffix(1/prefix(g))) computed inline.
// grid (16 bh, 4 slices), 256 thr.
// ---------------------------------------------------------------------------
__global__ __launch_bounds__(256) void k_amat(
    const float* __restrict__ kc, const float* __restrict__ vc,
    const float* __restrict__ gl, float* __restrict__ apart)
{
    const int tid = threadIdx.x, tx = tid & 15, ty = tid >> 4;
    const int bh = blockIdx.x, slc = blockIdx.y;
    const float* kb = kc + (size_t)bh * 65536;
    const float* vb = vc + (size_t)bh * 65536;

    __shared__ float sbuf[256];
    __shared__ float wfull[1024];
    __shared__ __align__(16) float vs[16][68];
    __shared__ __align__(16) float ks2[16][68];

    {
        const float4 g4 = ((const float4*)(gl + bh*1024))[tid];
        float g[4] = {g4.x, g4.y, g4.z, g4.w};
        float p[4];
        p[0]=g[0]; p[1]=p[0]+g[1]; p[2]=p[1]+g[2]; p[3]=p[2]+g[3];
        const float s = p[3];
        sbuf[tid] = s;
        __syncthreads();
        for (int off = 1; off < 256; off <<= 1) {
            float t = (tid >= off) ? sbuf[tid-off] : 0.0f;
            __syncthreads();
            sbuf[tid] += t;
            __syncthreads();
        }
        const float base = sbuf[tid] - s;
        float r[4], pr[4];
        #pragma unroll
        for (int u = 0; u < 4; ++u) r[u] = 1.0f / (base + p[u] + 1e-5f);
        pr[0]=r[0]; pr[1]=pr[0]+r[1]; pr[2]=pr[1]+r[2]; pr[3]=pr[2]+r[3];
        const float sr = pr[3];
        __syncthreads();
        sbuf[tid] = sr;
        __syncthreads();
        for (int off = 1; off < 256; off <<= 1) {
            float t = (tid >= off) ? sbuf[tid-off] : 0.0f;
            __syncthreads();
            sbuf[tid] += t;
            __syncthreads();
        }
        const float Rtot  = sbuf[255];
        const float baser = sbuf[tid] - sr;
        wfull[tid*4+0] = g[0] * (Rtot - (baser + pr[0]) + r[0]);
        wfull[tid*4+1] = g[1] * (Rtot - (baser + pr[1]) + r[1]);
        wfull[tid*4+2] = g[2] * (Rtot - (baser + pr[2]) + r[2]);
        wfull[tid*4+3] = g[3] * (Rtot - (baser + pr[3]) + r[3]);
    }
    __syncthreads();

    float acc[4][4] = {};
    const float4* k4 = (const float4*)kb;
    const float4* v4 = (const float4*)vb;
    for (int j0 = slc*256; j0 < slc*256 + 256; j0 += 16) {
        {
            int r = tid >> 4, c4 = tid & 15;
            *(float4*)&vs[r][c4*4]  = v4[(size_t)(j0 + r)*16 + c4];
            *(float4*)&ks2[r][c4*4] = k4[(size_t)(j0 + r)*16 + c4];
        }
        __syncthreads();
        #pragma unroll
        for (int jj = 0; jj < 16; ++jj) {
            float wj = wfull[j0 + jj];
            float a[4];
            a[0] = vs[jj][ty*4+0]*wj; a[1] = vs[jj][ty*4+1]*wj;
            a[2] = vs[jj][ty*4+2]*wj; a[3] = vs[jj][ty*4+3]*wj;
            float4 b4 = *(const float4*)&ks2[jj][tx*4];
            float bb[4] = {b4.x, b4.y, b4.z, b4.w};
            #pragma unroll
            for (int ii = 0; ii < 4; ++ii)
                #pragma unroll
                for (int jc = 0; jc < 4; ++jc)
                    acc[ii][jc] += a[ii] * bb[jc];
        }
        __syncthreads();
    }
    float* ap = apart + (size_t)(slc*16 + bh) * 4096;
    #pragma unroll
    for (int i = 0; i < 4; ++i) {
        float4 o = { acc[i][0], acc[i][1], acc[i][2], acc[i][3] };
        *(float4*)&ap[(ty*4+i)*64 + tx*4] = o;
    }
}

// ---------------------------------------------------------------------------
// K5: ctxt = q @ A (summing the 4 A-partials on load), row-normalize,
// write unit vectors as bf16 into [B,L,D] layout.  grid (16, 16), 256 thr.
// ---------------------------------------------------------------------------
__global__ __launch_bounds__(256) void k_ctxt(
    const float* __restrict__ q, const float* __restrict__ apart,
    unsigned short* __restrict__ ub)
{
    const int tid = threadIdx.x, tx = tid & 15, ty = tid >> 4;
    const int l0 = blockIdx.x * 64;
    const int bh = blockIdx.y;
    const float* qb = q + (size_t)bh * 65536;

    __shared__ float qs[64][17];
    __shared__ __align__(16) float As[16][68];
    float acc[4][4] = {};
    const float4* q4 = (const float4*)qb;
    const float4* a4 = (const float4*)apart;
    for (int d0 = 0; d0 < 64; d0 += 16) {
        {
            int r = tid >> 2, c4 = tid & 3;
            float4 t = q4[(size_t)(l0 + r)*16 + (d0 >> 2) + c4];
            qs[r][c4*4+0]=t.x; qs[r][c4*4+1]=t.y; qs[r][c4*4+2]=t.z; qs[r][c4*4+3]=t.w;
        }
        {
            int r = tid >> 4, c4 = tid & 15;
            size_t o = (size_t)(d0 + r)*16 + c4;
            float4 t0 = a4[(size_t)(0*16 + bh)*1024 + o];
            float4 t1 = a4[(size_t)(1*16 + bh)*1024 + o];
            float4 t2 = a4[(size_t)(2*16 + bh)*1024 + o];
            float4 t3 = a4[(size_t)(3*16 + bh)*1024 + o];
            float4 t;
            t.x = t0.x+t1.x+t2.x+t3.x; t.y = t0.y+t1.y+t2.y+t3.y;
            t.z = t0.z+t1.z+t2.z+t3.z; t.w = t0.w+t1.w+t2.w+t3.w;
            *(float4*)&As[r][c4*4] = t;
        }
        __syncthreads();
        #pragma unroll
        for (int dd = 0; dd < 16; ++dd) {
            float a[4];
            a[0] = qs[ty*4+0][dd]; a[1] = qs[ty*4+1][dd];
            a[2] = qs[ty*4+2][dd]; a[3] = qs[ty*4+3][dd];
            float4 b4 = *(const float4*)&As[dd][tx*4];
            float bb[4] = {b4.x, b4.y, b4.z, b4.w};
            #pragma unroll
            for (int ii = 0; ii < 4; ++ii)
                #pragma unroll
                for (int jj = 0; jj < 4; ++jj)
                    acc[ii][jj] += a[ii] * bb[jj];
        }
        __syncthreads();
    }
    __shared__ float red[64][17];
    __shared__ float nrm[64];
    #pragma unroll
    for (int i = 0; i < 4; ++i) {
        red[ty*4+i][tx] = acc[i][0]*acc[i][0] + acc[i][1]*acc[i][1]
                        + acc[i][2]*acc[i][2] + acc[i][3]*acc[i][3];
    }
    __syncthreads();
    if (tid < 64) {
        float s = 0.0f;
        #pragma unroll
        for (int t = 0; t < 16; ++t) s += red[tid][t];
        nrm[tid] = fmaxf(sqrtf(s), 1e-5f);
    }
    __syncthreads();
    const int b = bh >> 3, hd = bh & 7;
    #pragma unroll
    for (int i = 0; i < 4; ++i) {
        int lr = ty*4 + i;
        float inv = 1.0f / nrm[lr];
        ushort4 o;
        o.x = f2bf(acc[i][0]*inv); o.y = f2bf(acc[i][1]*inv);
        o.z = f2bf(acc[i][2]*inv); o.w = f2bf(acc[i][3]*inv);
        *(ushort4*)&ub[(size_t)(b*1024 + l0 + lr)*512 + hd*64 + tx*4] = o;
    }
}

// ---------------------------------------------------------------------------
// K6: out = Ub[2048][512](bf16) @ woT^T + wo_b via MFMA, 128x64 tiles.
// grid (8 nTiles, 16 mTiles) = 128 blocks, 256 thr = 4 waves.
// ---------------------------------------------------------------------------
__global__ __launch_bounds__(256) void k_out_mfma(
    const unsigned short* __restrict__ ub, const unsigned short* __restrict__ woT,
    const float* __restrict__ bo, float* __restrict__ out)
{
    const int tid = threadIdx.x;
    const int lane = tid & 63, wave = tid >> 6;
    const int q = lane >> 4, ln = lane & 15;
    const int wm = wave * 32;
    const int m0 = blockIdx.y * 128;
    const int n0 = blockIdx.x * 64;

    __shared__ unsigned short As[128*40];
    __shared__ unsigned short Bs[64*40];

    floatx4 acc[2][4];
    #pragma unroll
    for (int i = 0; i < 2; ++i)
        #pragma unroll
        for (int j = 0; j < 4; ++j)
            acc[i][j] = (floatx4){0.f, 0.f, 0.f, 0.f};

    const uint4* Ag = (const uint4*)ub;
    const uint4* Bg = (const uint4*)woT;
    for (int k0 = 0; k0 < 512; k0 += 32) {
        #pragma unroll
        for (int s = 0; s < 2; ++s) {
            int c = s*256 + tid;
            int r = c >> 2, cp = c & 3;
            uint4 va = Ag[(size_t)(m0 + r)*64 + (k0 >> 3) + cp];
            *(uint4*)&As[r*40 + cp*8] = va;
        }
        {
            int r = tid >> 2, cp = tid & 3;
            uint4 vb = Bg[(size_t)(n0 + r)*64 + (k0 >> 3) + cp];
            *(uint4*)&Bs[r*40 + cp*8] = vb;
        }
        __syncthreads();
        short8 af[2], bfr[4];
        #pragma unroll
        for (int i = 0; i < 2; ++i)
            af[i]  = *(const short8*)&As[(wm + i*16 + ln)*40 + q*8];
        #pragma unroll
        for (int i = 0; i < 4; ++i)
            bfr[i] = *(const short8*)&Bs[(i*16 + ln)*40 + q*8];
        #pragma unroll
        for (int mi = 0; mi < 2; ++mi)
            #pragma unroll
            for (int ni = 0; ni < 4; ++ni)
                acc[mi][ni] = __builtin_amdgcn_mfma_f32_16x16x32_bf16(
                    af[mi], bfr[ni], acc[mi][ni], 0, 0, 0);
        __syncthreads();
    }

    #pragma unroll
    for (int mi = 0; mi < 2; ++mi) {
        #pragma unroll
        for (int ni = 0; ni < 4; ++ni) {
            int gcol = n0 + ni*16 + ln;
            float bb = bo[gcol];
            #pragma unroll
            for (int reg = 0; reg < 4; ++reg) {
                int row = m0 + wm + mi*16 + q*4 + reg;
                out[(size_t)row*512 + gcol] = acc[mi][ni][reg] + bb;
            }
        }
    }
}

extern "C" void kernel_launch(void* const* d_in, const int* in_sizes, int n_in,
                              void* d_out, int out_size, void* d_ws, size_t ws_size,
                              hipStream_t stream)
{
    const float* x   = (const float*)d_in[0];
    const float* sb  = (const float*)d_in[1];
    const float* wq  = (const float*)d_in[2];
    const float* bq  = (const float*)d_in[3];
    const float* wk  = (const float*)d_in[4];
    const float* bk  = (const float*)d_in[5];
    const float* wv  = (const float*)d_in[6];
    const float* bv  = (const float*)d_in[7];
    const float* wo  = (const float*)d_in[8];
    const float* bo  = (const float*)d_in[9];
    const float* wg  = (const float*)d_in[10];
    const float* wgb = (const float*)d_in[11];
    float* out = (float*)d_out;
    float* ws  = (float*)d_ws;

    // workspace layout (float offsets)
    float* Q   = ws;                        // 1048576  [B,H,L,64] fp32
    float* KC  = ws + 1048576;              // 1048576  k_conv fp32
    float* VC  = ws + 2*1048576;            // 1048576  v_conv fp32
    float* GL  = ws + 3*1048576;            // 16384
    float* AP  = GL + 16384;                // 262144
    float* fp  = AP + 262144;
    unsigned short* XB  = (unsigned short*)fp;              // 2048*512 bf16
    unsigned short* WT  = XB  + 1048576;                    // 1536*512 bf16
    unsigned short* WOT = WT  + 786432;                     // 512*512 bf16
    unsigned short* UB  = WOT + 262144;                     // 2048*512 bf16
    unsigned short* UB2 = UB  + 1048576;                    // 2*16*64*1024 bf16
    unsigned short* TB  = UB2 + 2097152;                    // 8*1024*1024 bf16

    k_prep     <<<dim3(1024),   256, 0, stream>>>(x, wq, wk, wv, wo, sb,
                                                  XB, WT, WOT, TB);
    k_qkv_mfma <<<dim3(24, 16), 256, 0, stream>>>(XB, WT, bq, bk, bv, Q, UB2);
    k_conv_mfma<<<dim3(32, 16), 256, 0, stream>>>(TB, UB2, KC, VC);
    k_gate     <<<dim3(16, 16), 256, 0, stream>>>(KC, VC, wg, wgb, GL);
    k_amat     <<<dim3(16, 4),  256, 0, stream>>>(KC, VC, GL, AP);
    k_ctxt     <<<dim3(16, 16), 256, 0, stream>>>(Q, AP, UB);
    k_out_mfma <<<dim3(8, 16),  256, 0, stream>>>(UB, WOT, bo, out);
}

// Round 11
// 154.464 us; speedup vs baseline: 1.1354x; 1.0635x over previous
//
#include <hip/hip_runtime.h>
#include <math.h>

// Problem constants: B=2, L=1024, D=512, H=8, h=64, K=H=8, EPS=1e-5
// Layouts: q/kc/vc stored as [B*H][L][64] (bh*65536 + l*64 + d)
// UB2: bf16 conv inputs, d-major [tensor][bh][d=64][l=1024]
// TB:  bf16 Toeplitz filters [h=8][t=1024][s=1024], zero above diagonal
// KCB: bf16 k_conv, l-major [bh][l][64] (gate MFMA A-operand)

typedef __attribute__((ext_vector_type(8))) short short8;
typedef __attribute__((ext_vector_type(4))) float floatx4;

__device__ __forceinline__ unsigned short f2bf(float f) {
    unsigned int u = __float_as_uint(f);
    unsigned int r = (u + 0x7FFFu + ((u >> 16) & 1u)) >> 16;   // RNE
    return (unsigned short)r;
}

// ---------------------------------------------------------------------------
// K0: fused prep.  blocks 0-511: cast x -> bf16.  512-767: transpose+cast
// weights.  768-1023: Toeplitz filters TB.  1024: cast wg -> bf16.
// ---------------------------------------------------------------------------
__global__ __launch_bounds__(256) void k_prep(
    const float* __restrict__ x,
    const float* __restrict__ wq, const float* __restrict__ wk,
    const float* __restrict__ wv, const float* __restrict__ wo,
    const float* __restrict__ sb, const float* __restrict__ wg,
    unsigned short* __restrict__ xb,
    unsigned short* __restrict__ wT, unsigned short* __restrict__ woT,
    unsigned short* __restrict__ TB, unsigned short* __restrict__ wgb)
{
    __shared__ float sf[64][65];
    const int blk = blockIdx.x;
    const int tid = threadIdx.x;

    if (blk < 512) {                       // ---- castx ----
        const int gid = blk * 256 + tid;
        const float4* x4 = (const float4*)x;
        float4 a = x4[gid*2], b = x4[gid*2+1];
        uint4 o;
        o.x = f2bf(a.x) | ((unsigned)f2bf(a.y) << 16);
        o.y = f2bf(a.z) | ((unsigned)f2bf(a.w) << 16);
        o.z = f2bf(b.x) | ((unsigned)f2bf(b.y) << 16);
        o.w = f2bf(b.z) | ((unsigned)f2bf(b.w) << 16);
        ((uint4*)xb)[gid] = o;
    } else if (blk < 768) {                // ---- packw ----
        const int t = blk - 512;
        const float* src; unsigned short* dst; int n0, c0, k0;
        if (t < 192) {
            int nt = t >> 3, kt = t & 7;
            n0 = nt * 64; k0 = kt * 64;
            int z = n0 >> 9; c0 = n0 & 511;
            src = (z == 0) ? wq : (z == 1) ? wk : wv;
            dst = wT;
        } else {
            int u = t - 192; int nt = u >> 3, kt = u & 7;
            n0 = nt * 64; c0 = n0; k0 = kt * 64;
            src = wo; dst = woT;
        }
        const int rr = tid >> 4, c4 = tid & 15;
        #pragma unroll
        for (int g = 0; g < 4; ++g) {
            int r = g*16 + rr;
            float4 v = *(const float4*)&src[(size_t)(k0 + r)*512 + c0 + c4*4];
            sf[r][c4*4+0]=v.x; sf[r][c4*4+1]=v.y; sf[r][c4*4+2]=v.z; sf[r][c4*4+3]=v.w;
        }
        __syncthreads();
        #pragma unroll
        for (int g = 0; g < 4; ++g) {
            int c = g*16 + rr;
            int kk = c4*4;
            ushort4 o;
            o.x = f2bf(sf[kk+0][c]); o.y = f2bf(sf[kk+1][c]);
            o.z = f2bf(sf[kk+2][c]); o.w = f2bf(sf[kk+3][c]);
            *(ushort4*)&dst[(size_t)(n0 + c)*512 + k0 + kk] = o;
        }
    } else if (blk < 1024) {               // ---- mkT ----
        const int u = blk - 768;
        const int h = u >> 5;
        const int r0 = (u & 31) * 32;
        unsigned short* sbc = (unsigned short*)sf;     // 1024 ushorts
        for (int i = tid; i < 1024; i += 256)
            sbc[i] = f2bf(sb[i*8 + h]);
        __syncthreads();
        const int rr = tid >> 3, c0 = (tid & 7) * 128;
        const int t = r0 + rr;
        unsigned short* row = TB + ((size_t)h * 1024 + t) * 1024;
        for (int c = c0; c < c0 + 128; c += 8) {
            unsigned short v[8];
            #pragma unroll
            for (int j = 0; j < 8; ++j) {
                int s = c + j;
                v[j] = (t >= s) ? sbc[t - s] : (unsigned short)0;
            }
            uint4 o;
            o.x = v[0] | ((unsigned)v[1]<<16);
            o.y = v[2] | ((unsigned)v[3]<<16);
            o.z = v[4] | ((unsigned)v[5]<<16);
            o.w = v[6] | ((unsigned)v[7]<<16);
            *(uint4*)&row[c] = o;
        }
    } else {                               // ---- cast wg (4096 floats) ----
        const float4* wg4 = (const float4*)wg;
        for (int i = tid; i < 512; i += 256) {
            float4 a = wg4[i*2], b = wg4[i*2+1];
            uint4 o;
            o.x = f2bf(a.x) | ((unsigned)f2bf(a.y) << 16);
            o.y = f2bf(a.z) | ((unsigned)f2bf(a.w) << 16);
            o.z = f2bf(b.x) | ((unsigned)f2bf(b.y) << 16);
            o.w = f2bf(b.z) | ((unsigned)f2bf(b.w) << 16);
            ((uint4*)wgb)[i] = o;
        }
    }
}

// ---------------------------------------------------------------------------
// K1: QKV projection via MFMA, 128x64 tiles.  grid (24, 16), 256 thr.
// ---------------------------------------------------------------------------
__global__ __launch_bounds__(256) void k_qkv_mfma(
    const unsigned short* __restrict__ xb, const unsigned short* __restrict__ wT,
    const float* __restrict__ bq, const float* __restrict__ bk,
    const float* __restrict__ bv,
    float* __restrict__ qo, unsigned short* __restrict__ ub2)
{
    const int tid = threadIdx.x;
    const int lane = tid & 63, wave = tid >> 6;
    const int q = lane >> 4, ln = lane & 15;
    const int wm = wave * 32;
    const int m0 = blockIdx.y * 128;
    const int n0 = blockIdx.x * 64;

    __shared__ unsigned short As[128*40];
    __shared__ unsigned short Bs[64*40];

    floatx4 acc[2][4];
    #pragma unroll
    for (int i = 0; i < 2; ++i)
        #pragma unroll
        for (int j = 0; j < 4; ++j)
            acc[i][j] = (floatx4){0.f, 0.f, 0.f, 0.f};

    const uint4* Ag = (const uint4*)xb;
    const uint4* Bg = (const uint4*)wT;
    for (int k0 = 0; k0 < 512; k0 += 32) {
        #pragma unroll
        for (int s = 0; s < 2; ++s) {
            int c = s*256 + tid;
            int r = c >> 2, cp = c & 3;
            uint4 va = Ag[(size_t)(m0 + r)*64 + (k0 >> 3) + cp];
            *(uint4*)&As[r*40 + cp*8] = va;
        }
        {
            int r = tid >> 2, cp = tid & 3;
            uint4 vb = Bg[(size_t)(n0 + r)*64 + (k0 >> 3) + cp];
            *(uint4*)&Bs[r*40 + cp*8] = vb;
        }
        __syncthreads();
        short8 af[2], bfr[4];
        #pragma unroll
        for (int i = 0; i < 2; ++i)
            af[i]  = *(const short8*)&As[(wm + i*16 + ln)*40 + q*8];
        #pragma unroll
        for (int i = 0; i < 4; ++i)
            bfr[i] = *(const short8*)&Bs[(i*16 + ln)*40 + q*8];
        #pragma unroll
        for (int mi = 0; mi < 2; ++mi)
            #pragma unroll
            for (int ni = 0; ni < 4; ++ni)
                acc[mi][ni] = __builtin_amdgcn_mfma_f32_16x16x32_bf16(
                    af[mi], bfr[ni], acc[mi][ni], 0, 0, 0);
        __syncthreads();
    }

    const int z = n0 >> 9;                 // 64-col block never straddles
    if (z == 0) {
        #pragma unroll
        for (int mi = 0; mi < 2; ++mi) {
            #pragma unroll
            for (int ni = 0; ni < 4; ++ni) {
                int c = (n0 + ni*16 + ln) & 511;
                int head = c >> 6, dd = c & 63;
                float bb = bq[c];
                #pragma unroll
                for (int reg = 0; reg < 4; ++reg) {
                    int row = m0 + wm + mi*16 + q*4 + reg;
                    int b = row >> 10, l = row & 1023;
                    qo[(size_t)((b*8 + head)*1024 + l)*64 + dd] =
                        acc[mi][ni][reg] + bb;
                }
            }
        }
    } else {
        const float scale = (z == 1) ? 0.125f : 1.0f;
        const float* bias = (z == 1) ? bk : bv;
        unsigned short* dst = ub2 + (size_t)(z-1) * 16 * 64 * 1024;
        #pragma unroll
        for (int mi = 0; mi < 2; ++mi) {
            #pragma unroll
            for (int ni = 0; ni < 4; ++ni) {
                int c = (n0 + ni*16 + ln) & 511;
                int head = c >> 6, dd = c & 63;
                float bb = bias[c];
                int row0 = m0 + wm + mi*16 + q*4;
                int b = row0 >> 10, l0 = row0 & 1023;
                ushort4 o;
                o.x = f2bf((acc[mi][ni][0] + bb) * scale);
                o.y = f2bf((acc[mi][ni][1] + bb) * scale);
                o.z = f2bf((acc[mi][ni][2] + bb) * scale);
                o.w = f2bf((acc[mi][ni][3] + bb) * scale);
                *(ushort4*)&dst[((size_t)((b*8 + head)*64) + dd)*1024 + l0] = o;
            }
        }
    }
}

// ---------------------------------------------------------------------------
// K2: conv as Toeplitz GEMM, LDS-staged.  grid (32 bht, 16 tTiles), 256 thr.
// k-tensor blocks additionally write KCB (bf16) for the gate MFMA.
// ---------------------------------------------------------------------------
__global__ __launch_bounds__(256) void k_conv_mfma(
    const unsigned short* __restrict__ TB,
    const unsigned short* __restrict__ ub2,
    float* __restrict__ kc, float* __restrict__ vc,
    unsigned short* __restrict__ kcb)
{
    const int tid = threadIdx.x;
    const int lane = tid & 63, wave = tid >> 6;
    const int q = lane >> 4, ln = lane & 15;
    const int bht = blockIdx.x;
    const int it  = blockIdx.y;
    const int t0  = it * 64;
    const int bh  = bht & 15, h = bh & 7, tensor = bht >> 4;

    __shared__ unsigned short As[64*40];
    __shared__ unsigned short Bs[64*40];

    const uint4* Ag = (const uint4*)TB;    // 128 uint4 per 1024-elem row
    const uint4* Bg = (const uint4*)ub2;
    const size_t abase = (size_t)h * 131072 + (size_t)t0 * 128;
    const size_t bbase = (size_t)bht * 8192;

    floatx4 acc[4];
    #pragma unroll
    for (int i = 0; i < 4; ++i) acc[i] = (floatx4){0.f,0.f,0.f,0.f};

    const int kend = t0 + 64;
    const int r = tid >> 2, cp = tid & 3;
    for (int k0 = 0; k0 < kend; k0 += 32) {
        uint4 va = Ag[abase + (size_t)r*128 + (k0 >> 3) + cp];
        uint4 vb = Bg[bbase + (size_t)r*128 + (k0 >> 3) + cp];
        *(uint4*)&As[r*40 + cp*8] = va;
        *(uint4*)&Bs[r*40 + cp*8] = vb;
        __syncthreads();
        short8 a = *(const short8*)&As[(wave*16 + ln)*40 + q*8];
        short8 b0 = *(const short8*)&Bs[(0*16 + ln)*40 + q*8];
        short8 b1 = *(const short8*)&Bs[(1*16 + ln)*40 + q*8];
        short8 b2 = *(const short8*)&Bs[(2*16 + ln)*40 + q*8];
        short8 b3 = *(const short8*)&Bs[(3*16 + ln)*40 + q*8];
        acc[0] = __builtin_amdgcn_mfma_f32_16x16x32_bf16(a, b0, acc[0], 0, 0, 0);
        acc[1] = __builtin_amdgcn_mfma_f32_16x16x32_bf16(a, b1, acc[1], 0, 0, 0);
        acc[2] = __builtin_amdgcn_mfma_f32_16x16x32_bf16(a, b2, acc[2], 0, 0, 0);
        acc[3] = __builtin_amdgcn_mfma_f32_16x16x32_bf16(a, b3, acc[3], 0, 0, 0);
        __syncthreads();
    }

    float* dst = (tensor ? vc : kc) + (size_t)bh * 65536;
    #pragma unroll
    for (int ni = 0; ni < 4; ++ni)
        #pragma unroll
        for (int reg = 0; reg < 4; ++reg) {
            int row = t0 + wave*16 + q*4 + reg;
            dst[(size_t)row*64 + ni*16 + ln] = acc[ni][reg];
        }
    if (!tensor) {
        unsigned short* db = kcb + (size_t)bh * 65536;
        #pragma unroll
        for (int ni = 0; ni < 4; ++ni)
            #pragma unroll
            for (int reg = 0; reg < 4; ++reg) {
                int row = t0 + wave*16 + q*4 + reg;
                db[(size_t)row*64 + ni*16 + ln] = f2bf(acc[ni][reg]);
            }
    }
}

// ---------------------------------------------------------------------------
// K3: gate via MFMA.  T = KCb @ Wgb^T (K=64, one-shot LDS stage), then
// logit[l] = sum_m V[l][m]*T[l][m] (shuffle rowsum), g = relu^2 + eps.
// grid (16 lTiles, 16 bh), 256 thr = 4 waves (wave owns 16 l-rows).
// ---------------------------------------------------------------------------
__global__ __launch_bounds__(256) void k_gate_mfma(
    const unsigned short* __restrict__ kcb, const float* __restrict__ vc,
    const unsigned short* __restrict__ wgb, const float* __restrict__ wg_b,
    float* __restrict__ gl)
{
    const int tid = threadIdx.x;
    const int lane = tid & 63, wave = tid >> 6;
    const int q = lane >> 4, ln = lane & 15;
    const int l0 = blockIdx.x * 64;
    const int bh = blockIdx.y;

    __shared__ unsigned short As[64*72];   // stride 72: 2-way banks (free)
    __shared__ unsigned short Bs[64*72];

    const uint4* Ag = (const uint4*)(kcb + (size_t)bh * 65536);
    const uint4* Bg = (const uint4*)wgb;
    #pragma unroll
    for (int s = 0; s < 2; ++s) {
        int idx = s*256 + tid;
        int r = idx >> 3, cp = idx & 7;
        *(uint4*)&As[r*72 + cp*8] = Ag[(size_t)(l0 + r)*8 + cp];
        *(uint4*)&Bs[r*72 + cp*8] = Bg[r*8 + cp];
    }
    __syncthreads();

    floatx4 T[4];
    #pragma unroll
    for (int mt = 0; mt < 4; ++mt) T[mt] = (floatx4){0.f,0.f,0.f,0.f};
    #pragma unroll
    for (int k0 = 0; k0 < 64; k0 += 32) {
        short8 a = *(const short8*)&As[(wave*16 + ln)*72 + k0 + q*8];
        #pragma unroll
        for (int mt = 0; mt < 4; ++mt) {
            short8 b = *(const short8*)&Bs[(mt*16 + ln)*72 + k0 + q*8];
            T[mt] = __builtin_amdgcn_mfma_f32_16x16x32_bf16(a, b, T[mt], 0, 0, 0);
        }
    }

    // rowsum of V .* T   (lane holds cols m = mt*16+ln, rows l = wave*16+q*4+reg)
    const float* vb = vc + (size_t)bh * 65536;
    float part[4] = {0.f, 0.f, 0.f, 0.f};
    #pragma unroll
    for (int mt = 0; mt < 4; ++mt)
        #pragma unroll
        for (int reg = 0; reg < 4; ++reg) {
            int l = l0 + wave*16 + q*4 + reg;
            part[reg] += T[mt][reg] * vb[(size_t)l*64 + mt*16 + ln];
        }
    #pragma unroll
    for (int reg = 0; reg < 4; ++reg) {
        part[reg] += __shfl_xor(part[reg], 1);
        part[reg] += __shfl_xor(part[reg], 2);
        part[reg] += __shfl_xor(part[reg], 4);
        part[reg] += __shfl_xor(part[reg], 8);
    }
    if (ln == 0) {
        const float wgbias = wg_b[0];
        #pragma unroll
        for (int reg = 0; reg < 4; ++reg) {
            int l = l0 + wave*16 + q*4 + reg;
            float s = part[reg] + wgbias;
            float rr = fmaxf(s, 0.0f);
            gl[bh*1024 + l] = rr*rr + 1e-5f;
        }
    }
}

// ---------------------------------------------------------------------------
// K4: A_part[slc][bh] = sum_{j in slice} w_j * outer(v_conv[j], k_conv[j]),
// gate scan inline.  grid (16 bh, 8 slices of 128), 256 thr.
// ---------------------------------------------------------------------------
__global__ __launch_bounds__(256) void k_amat(
    const float* __restrict__ kc, const float* __restrict__ vc,
    const float* __restrict__ gl, float* __restrict__ apart)
{
    const int tid = threadIdx.x, tx = tid & 15, ty = tid >> 4;
    const int bh = blockIdx.x, slc = blockIdx.y;
    const float* kb = kc + (size_t)bh * 65536;
    const float* vb = vc + (size_t)bh * 65536;

    __shared__ float sbuf[256];
    __shared__ float wfull[1024];
    __shared__ __align__(16) float vs[16][68];
    __shared__ __align__(16) float ks2[16][68];

    {
        const float4 g4 = ((const float4*)(gl + bh*1024))[tid];
        float g[4] = {g4.x, g4.y, g4.z, g4.w};
        float p[4];
        p[0]=g[0]; p[1]=p[0]+g[1]; p[2]=p[1]+g[2]; p[3]=p[2]+g[3];
        const float s = p[3];
        sbuf[tid] = s;
        __syncthreads();
        for (int off = 1; off < 256; off <<= 1) {
            float t = (tid >= off) ? sbuf[tid-off] : 0.0f;
            __syncthreads();
            sbuf[tid] += t;
            __syncthreads();
        }
        const float base = sbuf[tid] - s;
        float r[4], pr[4];
        #pragma unroll
        for (int u = 0; u < 4; ++u) r[u] = 1.0f / (base + p[u] + 1e-5f);
        pr[0]=r[0]; pr[1]=pr[0]+r[1]; pr[2]=pr[1]+r[2]; pr[3]=pr[2]+r[3];
        const float sr = pr[3];
        __syncthreads();
        sbuf[tid] = sr;
        __syncthreads();
        for (int off = 1; off < 256; off <<= 1) {
            float t = (tid >= off) ? sbuf[tid-off] : 0.0f;
            __syncthreads();
            sbuf[tid] += t;
            __syncthreads();
        }
        const float Rtot  = sbuf[255];
        const float baser = sbuf[tid] - sr;
        wfull[tid*4+0] = g[0] * (Rtot - (baser + pr[0]) + r[0]);
        wfull[tid*4+1] = g[1] * (Rtot - (baser + pr[1]) + r[1]);
        wfull[tid*4+2] = g[2] * (Rtot - (baser + pr[2]) + r[2]);
        wfull[tid*4+3] = g[3] * (Rtot - (baser + pr[3]) + r[3]);
    }
    __syncthreads();

    float acc[4][4] = {};
    const float4* k4 = (const float4*)kb;
    const float4* v4 = (const float4*)vb;
    for (int j0 = slc*128; j0 < slc*128 + 128; j0 += 16) {
        {
            int r = tid >> 4, c4 = tid & 15;
            *(float4*)&vs[r][c4*4]  = v4[(size_t)(j0 + r)*16 + c4];
            *(float4*)&ks2[r][c4*4] = k4[(size_t)(j0 + r)*16 + c4];
        }
        __syncthreads();
        #pragma unroll
        for (int jj = 0; jj < 16; ++jj) {
            float wj = wfull[j0 + jj];
            float a[4];
            a[0] = vs[jj][ty*4+0]*wj; a[1] = vs[jj][ty*4+1]*wj;
            a[2] = vs[jj][ty*4+2]*wj; a[3] = vs[jj][ty*4+3]*wj;
            float4 b4 = *(const float4*)&ks2[jj][tx*4];
            float bb[4] = {b4.x, b4.y, b4.z, b4.w};
            #pragma unroll
            for (int ii = 0; ii < 4; ++ii)
                #pragma unroll
                for (int jc = 0; jc < 4; ++jc)
                    acc[ii][jc] += a[ii] * bb[jc];
        }
        __syncthreads();
    }
    float* ap = apart + (size_t)(slc*16 + bh) * 4096;
    #pragma unroll
    for (int i = 0; i < 4; ++i) {
        float4 o = { acc[i][0], acc[i][1], acc[i][2], acc[i][3] };
        *(float4*)&ap[(ty*4+i)*64 + tx*4] = o;
    }
}

// ---------------------------------------------------------------------------
// K5: ctxt = q @ A (summing the 8 A-partials on load), row-normalize,
// write unit vectors as bf16 into [B,L,D] layout.  grid (16, 16), 256 thr.
// ---------------------------------------------------------------------------
__global__ __launch_bounds__(256) void k_ctxt(
    const float* __restrict__ q, const float* __restrict__ apart,
    unsigned short* __restrict__ ub)
{
    const int tid = threadIdx.x, tx = tid & 15, ty = tid >> 4;
    const int l0 = blockIdx.x * 64;
    const int bh = blockIdx.y;
    const float* qb = q + (size_t)bh * 65536;

    __shared__ float qs[64][17];
    __shared__ __align__(16) float As[16][68];
    float acc[4][4] = {};
    const float4* q4 = (const float4*)qb;
    const float4* a4 = (const float4*)apart;
    for (int d0 = 0; d0 < 64; d0 += 16) {
        {
            int r = tid >> 2, c4 = tid & 3;
            float4 t = q4[(size_t)(l0 + r)*16 + (d0 >> 2) + c4];
            qs[r][c4*4+0]=t.x; qs[r][c4*4+1]=t.y; qs[r][c4*4+2]=t.z; qs[r][c4*4+3]=t.w;
        }
        {
            int r = tid >> 4, c4 = tid & 15;
            size_t o = (size_t)(d0 + r)*16 + c4;
            float4 t = a4[(size_t)(0*16 + bh)*1024 + o];
            #pragma unroll
            for (int s = 1; s < 8; ++s) {
                float4 u = a4[(size_t)(s*16 + bh)*1024 + o];
                t.x += u.x; t.y += u.y; t.z += u.z; t.w += u.w;
            }
            *(float4*)&As[r][c4*4] = t;
        }
        __syncthreads();
        #pragma unroll
        for (int dd = 0; dd < 16; ++dd) {
            float a[4];
            a[0] = qs[ty*4+0][dd]; a[1] = qs[ty*4+1][dd];
            a[2] = qs[ty*4+2][dd]; a[3] = qs[ty*4+3][dd];
            float4 b4 = *(const float4*)&As[dd][tx*4];
            float bb[4] = {b4.x, b4.y, b4.z, b4.w};
            #pragma unroll
            for (int ii = 0; ii < 4; ++ii)
                #pragma unroll
                for (int jj = 0; jj < 4; ++jj)
                    acc[ii][jj] += a[ii] * bb[jj];
        }
        __syncthreads();
    }
    __shared__ float red[64][17];
    __shared__ float nrm[64];
    #pragma unroll
    for (int i = 0; i < 4; ++i) {
        red[ty*4+i][tx] = acc[i][0]*acc[i][0] + acc[i][1]*acc[i][1]
                        + acc[i][2]*acc[i][2] + acc[i][3]*acc[i][3];
    }
    __syncthreads();
    if (tid < 64) {
        float s = 0.0f;
        #pragma unroll
        for (int t = 0; t < 16; ++t) s += red[tid][t];
        nrm[tid] = fmaxf(sqrtf(s), 1e-5f);
    }
    __syncthreads();
    const int b = bh >> 3, hd = bh & 7;
    #pragma unroll
    for (int i = 0; i < 4; ++i) {
        int lr = ty*4 + i;
        float inv = 1.0f / nrm[lr];
        ushort4 o;
        o.x = f2bf(acc[i][0]*inv); o.y = f2bf(acc[i][1]*inv);
        o.z = f2bf(acc[i][2]*inv); o.w = f2bf(acc[i][3]*inv);
        *(ushort4*)&ub[(size_t)(b*1024 + l0 + lr)*512 + hd*64 + tx*4] = o;
    }
}

// ---------------------------------------------------------------------------
// K6: out = Ub[2048][512](bf16) @ woT^T + wo_b via MFMA, 128x64 tiles.
// grid (8, 16), 256 thr.
// ---------------------------------------------------------------------------
__global__ __launch_bounds__(256) void k_out_mfma(
    const unsigned short* __restrict__ ub, const unsigned short* __restrict__ woT,
    const float* __restrict__ bo, float* __restrict__ out)
{
    const int tid = threadIdx.x;
    const int lane = tid & 63, wave = tid >> 6;
    const int q = lane >> 4, ln = lane & 15;
    const int wm = wave * 32;
    const int m0 = blockIdx.y * 128;
    const int n0 = blockIdx.x * 64;

    __shared__ unsigned short As[128*40];
    __shared__ unsigned short Bs[64*40];

    floatx4 acc[2][4];
    #pragma unroll
    for (int i = 0; i < 2; ++i)
        #pragma unroll
        for (int j = 0; j < 4; ++j)
            acc[i][j] = (floatx4){0.f, 0.f, 0.f, 0.f};

    const uint4* Ag = (const uint4*)ub;
    const uint4* Bg = (const uint4*)woT;
    for (int k0 = 0; k0 < 512; k0 += 32) {
        #pragma unroll
        for (int s = 0; s < 2; ++s) {
            int c = s*256 + tid;
            int r = c >> 2, cp = c & 3;
            uint4 va = Ag[(size_t)(m0 + r)*64 + (k0 >> 3) + cp];
            *(uint4*)&As[r*40 + cp*8] = va;
        }
        {
            int r = tid >> 2, cp = tid & 3;
            uint4 vb = Bg[(size_t)(n0 + r)*64 + (k0 >> 3) + cp];
            *(uint4*)&Bs[r*40 + cp*8] = vb;
        }
        __syncthreads();
        short8 af[2], bfr[4];
        #pragma unroll
        for (int i = 0; i < 2; ++i)
            af[i]  = *(const short8*)&As[(wm + i*16 + ln)*40 + q*8];
        #pragma unroll
        for (int i = 0; i < 4; ++i)
            bfr[i] = *(const short8*)&Bs[(i*16 + ln)*40 + q*8];
        #pragma unroll
        for (int mi = 0; mi < 2; ++mi)
            #pragma unroll
            for (int ni = 0; ni < 4; ++ni)
                acc[mi][ni] = __builtin_amdgcn_mfma_f32_16x16x32_bf16(
                    af[mi], bfr[ni], acc[mi][ni], 0, 0, 0);
        __syncthreads();
    }

    #pragma unroll
    for (int mi = 0; mi < 2; ++mi) {
        #pragma unroll
        for (int ni = 0; ni < 4; ++ni) {
            int gcol = n0 + ni*16 + ln;
            float bb = bo[gcol];
            #pragma unroll
            for (int reg = 0; reg < 4; ++reg) {
                int row = m0 + wm + mi*16 + q*4 + reg;
                out[(size_t)row*512 + gcol] = acc[mi][ni][reg] + bb;
            }
        }
    }
}

extern "C" void kernel_launch(void* const* d_in, const int* in_sizes, int n_in,
                              void* d_out, int out_size, void* d_ws, size_t ws_size,
                              hipStream_t stream)
{
    const float* x   = (const float*)d_in[0];
    const float* sb  = (const float*)d_in[1];
    const float* wq  = (const float*)d_in[2];
    const float* bq  = (const float*)d_in[3];
    const float* wk  = (const float*)d_in[4];
    const float* bk  = (const float*)d_in[5];
    const float* wv  = (const float*)d_in[6];
    const float* bv  = (const float*)d_in[7];
    const float* wo  = (const float*)d_in[8];
    const float* bo  = (const float*)d_in[9];
    const float* wg  = (const float*)d_in[10];
    const float* wgb = (const float*)d_in[11];
    float* out = (float*)d_out;
    float* ws  = (float*)d_ws;

    // workspace layout (float offsets)
    float* Q   = ws;                        // 1048576  [B,H,L,64] fp32
    float* KC  = ws + 1048576;              // 1048576  k_conv fp32
    float* VC  = ws + 2*1048576;            // 1048576  v_conv fp32
    float* GL  = ws + 3*1048576;            // 16384
    float* AP  = GL + 16384;                // 8*65536 = 524288
    float* fp  = AP + 524288;
    unsigned short* XB  = (unsigned short*)fp;              // 2048*512 bf16
    unsigned short* WT  = XB  + 1048576;                    // 1536*512 bf16
    unsigned short* WOT = WT  + 786432;                     // 512*512 bf16
    unsigned short* UB  = WOT + 262144;                     // 2048*512 bf16
    unsigned short* UB2 = UB  + 1048576;                    // 2*16*64*1024 bf16
    unsigned short* TB  = UB2 + 2097152;                    // 8*1024*1024 bf16
    unsigned short* WGB = TB  + 8388608;                    // 4096 bf16
    unsigned short* KCB = WGB + 4096;                       // 16*1024*64 bf16

    k_prep     <<<dim3(1025),   256, 0, stream>>>(x, wq, wk, wv, wo, sb, wg,
                                                  XB, WT, WOT, TB, WGB);
    k_qkv_mfma <<<dim3(24, 16), 256, 0, stream>>>(XB, WT, bq, bk, bv, Q, UB2);
    k_conv_mfma<<<dim3(32, 16), 256, 0, stream>>>(TB, UB2, KC, VC, KCB);
    k_gate_mfma<<<dim3(16, 16), 256, 0, stream>>>(KCB, VC, WGB, wgb, GL);
    k_amat     <<<dim3(16, 8),  256, 0, stream>>>(KC, VC, GL, AP);
    k_ctxt     <<<dim3(16, 16), 256, 0, stream>>>(Q, AP, UB);
    k_out_mfma <<<dim3(8, 16),  256, 0, stream>>>(UB, WOT, bo, out);
}

// Round 12
// 152.218 us; speedup vs baseline: 1.1521x; 1.0148x over previous
//
#include <hip/hip_runtime.h>
#include <math.h>

// Problem constants: B=2, L=1024, D=512, H=8, h=64, K=H=8, EPS=1e-5
// Layouts: q/kc/vc stored as [B*H][L][64] (bh*65536 + l*64 + d)
// UB2: bf16 conv inputs, d-major [tensor][bh][d=64][l=1024]
// TB:  bf16 Toeplitz filters [h=8][t=1024][s=1024], zero above diagonal
// KCB: bf16 k_conv, l-major [bh][l][64] (gate MFMA A-operand)

typedef __attribute__((ext_vector_type(8))) short short8;
typedef __attribute__((ext_vector_type(4))) float floatx4;

__device__ __forceinline__ unsigned short f2bf(float f) {
    unsigned int u = __float_as_uint(f);
    unsigned int r = (u + 0x7FFFu + ((u >> 16) & 1u)) >> 16;   // RNE
    return (unsigned short)r;
}

// ---------------------------------------------------------------------------
// K0: fused prep.  blocks 0-511: cast x -> bf16.  512-767: transpose+cast
// weights.  768-1023: Toeplitz filters TB.  1024: cast wg -> bf16.
// ---------------------------------------------------------------------------
__global__ __launch_bounds__(256) void k_prep(
    const float* __restrict__ x,
    const float* __restrict__ wq, const float* __restrict__ wk,
    const float* __restrict__ wv, const float* __restrict__ wo,
    const float* __restrict__ sb, const float* __restrict__ wg,
    unsigned short* __restrict__ xb,
    unsigned short* __restrict__ wT, unsigned short* __restrict__ woT,
    unsigned short* __restrict__ TB, unsigned short* __restrict__ wgb)
{
    __shared__ float sf[64][65];
    const int blk = blockIdx.x;
    const int tid = threadIdx.x;

    if (blk < 512) {                       // ---- castx ----
        const int gid = blk * 256 + tid;
        const float4* x4 = (const float4*)x;
        float4 a = x4[gid*2], b = x4[gid*2+1];
        uint4 o;
        o.x = f2bf(a.x) | ((unsigned)f2bf(a.y) << 16);
        o.y = f2bf(a.z) | ((unsigned)f2bf(a.w) << 16);
        o.z = f2bf(b.x) | ((unsigned)f2bf(b.y) << 16);
        o.w = f2bf(b.z) | ((unsigned)f2bf(b.w) << 16);
        ((uint4*)xb)[gid] = o;
    } else if (blk < 768) {                // ---- packw ----
        const int t = blk - 512;
        const float* src; unsigned short* dst; int n0, c0, k0;
        if (t < 192) {
            int nt = t >> 3, kt = t & 7;
            n0 = nt * 64; k0 = kt * 64;
            int z = n0 >> 9; c0 = n0 & 511;
            src = (z == 0) ? wq : (z == 1) ? wk : wv;
            dst = wT;
        } else {
            int u = t - 192; int nt = u >> 3, kt = u & 7;
            n0 = nt * 64; c0 = n0; k0 = kt * 64;
            src = wo; dst = woT;
        }
        const int rr = tid >> 4, c4 = tid & 15;
        #pragma unroll
        for (int g = 0; g < 4; ++g) {
            int r = g*16 + rr;
            float4 v = *(const float4*)&src[(size_t)(k0 + r)*512 + c0 + c4*4];
            sf[r][c4*4+0]=v.x; sf[r][c4*4+1]=v.y; sf[r][c4*4+2]=v.z; sf[r][c4*4+3]=v.w;
        }
        __syncthreads();
        #pragma unroll
        for (int g = 0; g < 4; ++g) {
            int c = g*16 + rr;
            int kk = c4*4;
            ushort4 o;
            o.x = f2bf(sf[kk+0][c]); o.y = f2bf(sf[kk+1][c]);
            o.z = f2bf(sf[kk+2][c]); o.w = f2bf(sf[kk+3][c]);
            *(ushort4*)&dst[(size_t)(n0 + c)*512 + k0 + kk] = o;
        }
    } else if (blk < 1024) {               // ---- mkT ----
        const int u = blk - 768;
        const int h = u >> 5;
        const int r0 = (u & 31) * 32;
        unsigned short* sbc = (unsigned short*)sf;     // 1024 ushorts
        for (int i = tid; i < 1024; i += 256)
            sbc[i] = f2bf(sb[i*8 + h]);
        __syncthreads();
        const int rr = tid >> 3, c0 = (tid & 7) * 128;
        const int t = r0 + rr;
        unsigned short* row = TB + ((size_t)h * 1024 + t) * 1024;
        for (int c = c0; c < c0 + 128; c += 8) {
            unsigned short v[8];
            #pragma unroll
            for (int j = 0; j < 8; ++j) {
                int s = c + j;
                v[j] = (t >= s) ? sbc[t - s] : (unsigned short)0;
            }
            uint4 o;
            o.x = v[0] | ((unsigned)v[1]<<16);
            o.y = v[2] | ((unsigned)v[3]<<16);
            o.z = v[4] | ((unsigned)v[5]<<16);
            o.w = v[6] | ((unsigned)v[7]<<16);
            *(uint4*)&row[c] = o;
        }
    } else {                               // ---- cast wg (4096 floats) ----
        const float4* wg4 = (const float4*)wg;
        for (int i = tid; i < 512; i += 256) {
            float4 a = wg4[i*2], b = wg4[i*2+1];
            uint4 o;
            o.x = f2bf(a.x) | ((unsigned)f2bf(a.y) << 16);
            o.y = f2bf(a.z) | ((unsigned)f2bf(a.w) << 16);
            o.z = f2bf(b.x) | ((unsigned)f2bf(b.y) << 16);
            o.w = f2bf(b.z) | ((unsigned)f2bf(b.w) << 16);
            ((uint4*)wgb)[i] = o;
        }
    }
}

// ---------------------------------------------------------------------------
// K1: QKV projection via MFMA, 128x64 tiles, K-step 64 (2 chunks/barrier).
// grid (24, 16), 256 thr.  Chunk order per accumulator matches the K-step-32
// variant -> bit-identical outputs.
// ---------------------------------------------------------------------------
__global__ __launch_bounds__(256) void k_qkv_mfma(
    const unsigned short* __restrict__ xb, const unsigned short* __restrict__ wT,
    const float* __restrict__ bq, const float* __restrict__ bk,
    const float* __restrict__ bv,
    float* __restrict__ qo, unsigned short* __restrict__ ub2)
{
    const int tid = threadIdx.x;
    const int lane = tid & 63, wave = tid >> 6;
    const int q = lane >> 4, ln = lane & 15;
    const int wm = wave * 32;
    const int m0 = blockIdx.y * 128;
    const int n0 = blockIdx.x * 64;

    __shared__ unsigned short As[128*72];   // 128 rows x 64 k (+8 pad)
    __shared__ unsigned short Bs[64*72];

    floatx4 acc[2][4];
    #pragma unroll
    for (int i = 0; i < 2; ++i)
        #pragma unroll
        for (int j = 0; j < 4; ++j)
            acc[i][j] = (floatx4){0.f, 0.f, 0.f, 0.f};

    const uint4* Ag = (const uint4*)xb;
    const uint4* Bg = (const uint4*)wT;
    for (int k0 = 0; k0 < 512; k0 += 64) {
        #pragma unroll
        for (int s = 0; s < 4; ++s) {
            int idx = s*256 + tid;
            int r = idx >> 3, cp = idx & 7;
            uint4 va = Ag[(size_t)(m0 + r)*64 + (k0 >> 3) + cp];
            *(uint4*)&As[r*72 + cp*8] = va;
        }
        #pragma unroll
        for (int s = 0; s < 2; ++s) {
            int idx = s*256 + tid;
            int r = idx >> 3, cp = idx & 7;
            uint4 vb = Bg[(size_t)(n0 + r)*64 + (k0 >> 3) + cp];
            *(uint4*)&Bs[r*72 + cp*8] = vb;
        }
        __syncthreads();
        short8 af0[2], af1[2], bf0[4], bf1[4];
        #pragma unroll
        for (int i = 0; i < 2; ++i) {
            af0[i] = *(const short8*)&As[(wm + i*16 + ln)*72 + q*8];
            af1[i] = *(const short8*)&As[(wm + i*16 + ln)*72 + 32 + q*8];
        }
        #pragma unroll
        for (int i = 0; i < 4; ++i) {
            bf0[i] = *(const short8*)&Bs[(i*16 + ln)*72 + q*8];
            bf1[i] = *(const short8*)&Bs[(i*16 + ln)*72 + 32 + q*8];
        }
        #pragma unroll
        for (int mi = 0; mi < 2; ++mi)
            #pragma unroll
            for (int ni = 0; ni < 4; ++ni) {
                acc[mi][ni] = __builtin_amdgcn_mfma_f32_16x16x32_bf16(
                    af0[mi], bf0[ni], acc[mi][ni], 0, 0, 0);
                acc[mi][ni] = __builtin_amdgcn_mfma_f32_16x16x32_bf16(
                    af1[mi], bf1[ni], acc[mi][ni], 0, 0, 0);
            }
        __syncthreads();
    }

    const int z = n0 >> 9;                 // 64-col block never straddles
    if (z == 0) {
        #pragma unroll
        for (int mi = 0; mi < 2; ++mi) {
            #pragma unroll
            for (int ni = 0; ni < 4; ++ni) {
                int c = (n0 + ni*16 + ln) & 511;
                int head = c >> 6, dd = c & 63;
                float bb = bq[c];
                #pragma unroll
                for (int reg = 0; reg < 4; ++reg) {
                    int row = m0 + wm + mi*16 + q*4 + reg;
                    int b = row >> 10, l = row & 1023;
                    qo[(size_t)((b*8 + head)*1024 + l)*64 + dd] =
                        acc[mi][ni][reg] + bb;
                }
            }
        }
    } else {
        const float scale = (z == 1) ? 0.125f : 1.0f;
        const float* bias = (z == 1) ? bk : bv;
        unsigned short* dst = ub2 + (size_t)(z-1) * 16 * 64 * 1024;
        #pragma unroll
        for (int mi = 0; mi < 2; ++mi) {
            #pragma unroll
            for (int ni = 0; ni < 4; ++ni) {
                int c = (n0 + ni*16 + ln) & 511;
                int head = c >> 6, dd = c & 63;
                float bb = bias[c];
                int row0 = m0 + wm + mi*16 + q*4;
                int b = row0 >> 10, l0 = row0 & 1023;
                ushort4 o;
                o.x = f2bf((acc[mi][ni][0] + bb) * scale);
                o.y = f2bf((acc[mi][ni][1] + bb) * scale);
                o.z = f2bf((acc[mi][ni][2] + bb) * scale);
                o.w = f2bf((acc[mi][ni][3] + bb) * scale);
                *(ushort4*)&dst[((size_t)((b*8 + head)*64) + dd)*1024 + l0] = o;
            }
        }
    }
}

// ---------------------------------------------------------------------------
// K2: conv as Toeplitz GEMM, LDS-staged, K-step 64.  grid (32 bht, 16 it),
// 256 thr.  kend = t0+64 is always a multiple of 64.  k-tensor blocks also
// write KCB (bf16) for the gate MFMA.
// ---------------------------------------------------------------------------
__global__ __launch_bounds__(256) void k_conv_mfma(
    const unsigned short* __restrict__ TB,
    const unsigned short* __restrict__ ub2,
    float* __restrict__ kc, float* __restrict__ vc,
    unsigned short* __restrict__ kcb)
{
    const int tid = threadIdx.x;
    const int lane = tid & 63, wave = tid >> 6;
    const int q = lane >> 4, ln = lane & 15;
    const int bht = blockIdx.x;
    const int it  = blockIdx.y;
    const int t0  = it * 64;
    const int bh  = bht & 15, h = bh & 7, tensor = bht >> 4;

    __shared__ unsigned short As[64*72];
    __shared__ unsigned short Bs[64*72];

    const uint4* Ag = (const uint4*)TB;    // 128 uint4 per 1024-elem row
    const uint4* Bg = (const uint4*)ub2;
    const size_t abase = (size_t)h * 131072 + (size_t)t0 * 128;
    const size_t bbase = (size_t)bht * 8192;

    floatx4 acc[4];
    #pragma unroll
    for (int i = 0; i < 4; ++i) acc[i] = (floatx4){0.f,0.f,0.f,0.f};

    const int kend = t0 + 64;
    for (int k0 = 0; k0 < kend; k0 += 64) {
        #pragma unroll
        for (int s = 0; s < 2; ++s) {
            int idx = s*256 + tid;
            int r = idx >> 3, cp = idx & 7;
            uint4 va = Ag[abase + (size_t)r*128 + (k0 >> 3) + cp];
            uint4 vb = Bg[bbase + (size_t)r*128 + (k0 >> 3) + cp];
            *(uint4*)&As[r*72 + cp*8] = va;
            *(uint4*)&Bs[r*72 + cp*8] = vb;
        }
        __syncthreads();
        short8 a0 = *(const short8*)&As[(wave*16 + ln)*72 + q*8];
        short8 a1 = *(const short8*)&As[(wave*16 + ln)*72 + 32 + q*8];
        #pragma unroll
        for (int ni = 0; ni < 4; ++ni) {
            short8 b0 = *(const short8*)&Bs[(ni*16 + ln)*72 + q*8];
            short8 b1 = *(const short8*)&Bs[(ni*16 + ln)*72 + 32 + q*8];
            acc[ni] = __builtin_amdgcn_mfma_f32_16x16x32_bf16(a0, b0, acc[ni], 0, 0, 0);
            acc[ni] = __builtin_amdgcn_mfma_f32_16x16x32_bf16(a1, b1, acc[ni], 0, 0, 0);
        }
        __syncthreads();
    }

    float* dst = (tensor ? vc : kc) + (size_t)bh * 65536;
    #pragma unroll
    for (int ni = 0; ni < 4; ++ni)
        #pragma unroll
        for (int reg = 0; reg < 4; ++reg) {
            int row = t0 + wave*16 + q*4 + reg;
            dst[(size_t)row*64 + ni*16 + ln] = acc[ni][reg];
        }
    if (!tensor) {
        unsigned short* db = kcb + (size_t)bh * 65536;
        #pragma unroll
        for (int ni = 0; ni < 4; ++ni)
            #pragma unroll
            for (int reg = 0; reg < 4; ++reg) {
                int row = t0 + wave*16 + q*4 + reg;
                db[(size_t)row*64 + ni*16 + ln] = f2bf(acc[ni][reg]);
            }
    }
}

// ---------------------------------------------------------------------------
// K3: gate via MFMA.  T = KCb @ Wgb^T (K=64, one-shot LDS stage), then
// logit[l] = sum_m V[l][m]*T[l][m] (shuffle rowsum), g = relu^2 + eps.
// grid (16 lTiles, 16 bh), 256 thr = 4 waves.
// ---------------------------------------------------------------------------
__global__ __launch_bounds__(256) void k_gate_mfma(
    const unsigned short* __restrict__ kcb, const float* __restrict__ vc,
    const unsigned short* __restrict__ wgb, const float* __restrict__ wg_b,
    float* __restrict__ gl)
{
    const int tid = threadIdx.x;
    const int lane = tid & 63, wave = tid >> 6;
    const int q = lane >> 4, ln = lane & 15;
    const int l0 = blockIdx.x * 64;
    const int bh = blockIdx.y;

    __shared__ unsigned short As[64*72];   // stride 72: 2-way banks (free)
    __shared__ unsigned short Bs[64*72];

    const uint4* Ag = (const uint4*)(kcb + (size_t)bh * 65536);
    const uint4* Bg = (const uint4*)wgb;
    #pragma unroll
    for (int s = 0; s < 2; ++s) {
        int idx = s*256 + tid;
        int r = idx >> 3, cp = idx & 7;
        *(uint4*)&As[r*72 + cp*8] = Ag[(size_t)(l0 + r)*8 + cp];
        *(uint4*)&Bs[r*72 + cp*8] = Bg[r*8 + cp];
    }
    __syncthreads();

    floatx4 T[4];
    #pragma unroll
    for (int mt = 0; mt < 4; ++mt) T[mt] = (floatx4){0.f,0.f,0.f,0.f};
    #pragma unroll
    for (int k0 = 0; k0 < 64; k0 += 32) {
        short8 a = *(const short8*)&As[(wave*16 + ln)*72 + k0 + q*8];
        #pragma unroll
        for (int mt = 0; mt < 4; ++mt) {
            short8 b = *(const short8*)&Bs[(mt*16 + ln)*72 + k0 + q*8];
            T[mt] = __builtin_amdgcn_mfma_f32_16x16x32_bf16(a, b, T[mt], 0, 0, 0);
        }
    }

    // rowsum of V .* T   (lane holds cols m = mt*16+ln, rows l = wave*16+q*4+reg)
    const float* vb = vc + (size_t)bh * 65536;
    float part[4] = {0.f, 0.f, 0.f, 0.f};
    #pragma unroll
    for (int mt = 0; mt < 4; ++mt)
        #pragma unroll
        for (int reg = 0; reg < 4; ++reg) {
            int l = l0 + wave*16 + q*4 + reg;
            part[reg] += T[mt][reg] * vb[(size_t)l*64 + mt*16 + ln];
        }
    #pragma unroll
    for (int reg = 0; reg < 4; ++reg) {
        part[reg] += __shfl_xor(part[reg], 1);
        part[reg] += __shfl_xor(part[reg], 2);
        part[reg] += __shfl_xor(part[reg], 4);
        part[reg] += __shfl_xor(part[reg], 8);
    }
    if (ln == 0) {
        const float wgbias = wg_b[0];
        #pragma unroll
        for (int reg = 0; reg < 4; ++reg) {
            int l = l0 + wave*16 + q*4 + reg;
            float s = part[reg] + wgbias;
            float rr = fmaxf(s, 0.0f);
            gl[bh*1024 + l] = rr*rr + 1e-5f;
        }
    }
}

// ---------------------------------------------------------------------------
// K4: A_part[slc][bh] = sum_{j in slice} w_j * outer(v_conv[j], k_conv[j]),
// gate scan inline.  grid (16 bh, 8 slices of 128), 256 thr.
// ---------------------------------------------------------------------------
__global__ __launch_bounds__(256) void k_amat(
    const float* __restrict__ kc, const float* __restrict__ vc,
    const float* __restrict__ gl, float* __restrict__ apart)
{
    const int tid = threadIdx.x, tx = tid & 15, ty = tid >> 4;
    const int bh = blockIdx.x, slc = blockIdx.y;
    const float* kb = kc + (size_t)bh * 65536;
    const float* vb = vc + (size_t)bh * 65536;

    __shared__ float sbuf[256];
    __shared__ float wfull[1024];
    __shared__ __align__(16) float vs[16][68];
    __shared__ __align__(16) float ks2[16][68];

    {
        const float4 g4 = ((const float4*)(gl + bh*1024))[tid];
        float g[4] = {g4.x, g4.y, g4.z, g4.w};
        float p[4];
        p[0]=g[0]; p[1]=p[0]+g[1]; p[2]=p[1]+g[2]; p[3]=p[2]+g[3];
        const float s = p[3];
        sbuf[tid] = s;
        __syncthreads();
        for (int off = 1; off < 256; off <<= 1) {
            float t = (tid >= off) ? sbuf[tid-off] : 0.0f;
            __syncthreads();
            sbuf[tid] += t;
            __syncthreads();
        }
        const float base = sbuf[tid] - s;
        float r[4], pr[4];
        #pragma unroll
        for (int u = 0; u < 4; ++u) r[u] = 1.0f / (base + p[u] + 1e-5f);
        pr[0]=r[0]; pr[1]=pr[0]+r[1]; pr[2]=pr[1]+r[2]; pr[3]=pr[2]+r[3];
        const float sr = pr[3];
        __syncthreads();
        sbuf[tid] = sr;
        __syncthreads();
        for (int off = 1; off < 256; off <<= 1) {
            float t = (tid >= off) ? sbuf[tid-off] : 0.0f;
            __syncthreads();
            sbuf[tid] += t;
            __syncthreads();
        }
        const float Rtot  = sbuf[255];
        const float baser = sbuf[tid] - sr;
        wfull[tid*4+0] = g[0] * (Rtot - (baser + pr[0]) + r[0]);
        wfull[tid*4+1] = g[1] * (Rtot - (baser + pr[1]) + r[1]);
        wfull[tid*4+2] = g[2] * (Rtot - (baser + pr[2]) + r[2]);
        wfull[tid*4+3] = g[3] * (Rtot - (baser + pr[3]) + r[3]);
    }
    __syncthreads();

    float acc[4][4] = {};
    const float4* k4 = (const float4*)kb;
    const float4* v4 = (const float4*)vb;
    for (int j0 = slc*128; j0 < slc*128 + 128; j0 += 16) {
        {
            int r = tid >> 4, c4 = tid & 15;
            *(float4*)&vs[r][c4*4]  = v4[(size_t)(j0 + r)*16 + c4];
            *(float4*)&ks2[r][c4*4] = k4[(size_t)(j0 + r)*16 + c4];
        }
        __syncthreads();
        #pragma unroll
        for (int jj = 0; jj < 16; ++jj) {
            float wj = wfull[j0 + jj];
            float a[4];
            a[0] = vs[jj][ty*4+0]*wj; a[1] = vs[jj][ty*4+1]*wj;
            a[2] = vs[jj][ty*4+2]*wj; a[3] = vs[jj][ty*4+3]*wj;
            float4 b4 = *(const float4*)&ks2[jj][tx*4];
            float bb[4] = {b4.x, b4.y, b4.z, b4.w};
            #pragma unroll
            for (int ii = 0; ii < 4; ++ii)
                #pragma unroll
                for (int jc = 0; jc < 4; ++jc)
                    acc[ii][jc] += a[ii] * bb[jc];
        }
        __syncthreads();
    }
    float* ap = apart + (size_t)(slc*16 + bh) * 4096;
    #pragma unroll
    for (int i = 0; i < 4; ++i) {
        float4 o = { acc[i][0], acc[i][1], acc[i][2], acc[i][3] };
        *(float4*)&ap[(ty*4+i)*64 + tx*4] = o;
    }
}

// ---------------------------------------------------------------------------
// K5: ctxt = q @ A (summing the 8 A-partials on load), row-normalize,
// write unit vectors as bf16 into [B,L,D] layout.  grid (16, 16), 256 thr.
// q-rows register-blocked (float4 LDS reads; qs stride 20 for 16B alignment).
// ---------------------------------------------------------------------------
__global__ __launch_bounds__(256) void k_ctxt(
    const float* __restrict__ q, const float* __restrict__ apart,
    unsigned short* __restrict__ ub)
{
    const int tid = threadIdx.x, tx = tid & 15, ty = tid >> 4;
    const int l0 = blockIdx.x * 64;
    const int bh = blockIdx.y;
    const float* qb = q + (size_t)bh * 65536;

    __shared__ __align__(16) float qs[64][20];
    __shared__ __align__(16) float As[16][68];
    float acc[4][4] = {};
    const float4* q4 = (const float4*)qb;
    const float4* a4 = (const float4*)apart;
    for (int d0 = 0; d0 < 64; d0 += 16) {
        {
            int r = tid >> 2, c4 = tid & 3;
            float4 t = q4[(size_t)(l0 + r)*16 + (d0 >> 2) + c4];
            *(float4*)&qs[r][c4*4] = t;
        }
        {
            int r = tid >> 4, c4 = tid & 15;
            size_t o = (size_t)(d0 + r)*16 + c4;
            float4 t = a4[(size_t)(0*16 + bh)*1024 + o];
            #pragma unroll
            for (int s = 1; s < 8; ++s) {
                float4 u = a4[(size_t)(s*16 + bh)*1024 + o];
                t.x += u.x; t.y += u.y; t.z += u.z; t.w += u.w;
            }
            *(float4*)&As[r][c4*4] = t;
        }
        __syncthreads();
        // register-block q: rows ty*4+i, 16 cols of this d0 chunk
        float qreg[4][16];
        #pragma unroll
        for (int i = 0; i < 4; ++i)
            #pragma unroll
            for (int c = 0; c < 4; ++c) {
                float4 t = *(const float4*)&qs[ty*4+i][c*4];
                qreg[i][c*4+0] = t.x; qreg[i][c*4+1] = t.y;
                qreg[i][c*4+2] = t.z; qreg[i][c*4+3] = t.w;
            }
        #pragma unroll
        for (int dd = 0; dd < 16; ++dd) {
            float4 b4 = *(const float4*)&As[dd][tx*4];
            float bb[4] = {b4.x, b4.y, b4.z, b4.w};
            #pragma unroll
            for (int ii = 0; ii < 4; ++ii)
                #pragma unroll
                for (int jj = 0; jj < 4; ++jj)
                    acc[ii][jj] += qreg[ii][dd] * bb[jj];
        }
        __syncthreads();
    }
    __shared__ float red[64][17];
    __shared__ float nrm[64];
    #pragma unroll
    for (int i = 0; i < 4; ++i) {
        red[ty*4+i][tx] = acc[i][0]*acc[i][0] + acc[i][1]*acc[i][1]
                        + acc[i][2]*acc[i][2] + acc[i][3]*acc[i][3];
    }
    __syncthreads();
    if (tid < 64) {
        float s = 0.0f;
        #pragma unroll
        for (int t = 0; t < 16; ++t) s += red[tid][t];
        nrm[tid] = fmaxf(sqrtf(s), 1e-5f);
    }
    __syncthreads();
    const int b = bh >> 3, hd = bh & 7;
    #pragma unroll
    for (int i = 0; i < 4; ++i) {
        int lr = ty*4 + i;
        float inv = 1.0f / nrm[lr];
        ushort4 o;
        o.x = f2bf(acc[i][0]*inv); o.y = f2bf(acc[i][1]*inv);
        o.z = f2bf(acc[i][2]*inv); o.w = f2bf(acc[i][3]*inv);
        *(ushort4*)&ub[(size_t)(b*1024 + l0 + lr)*512 + hd*64 + tx*4] = o;
    }
}

// ---------------------------------------------------------------------------
// K6: out = Ub[2048][512](bf16) @ woT^T + wo_b via MFMA, 128x64 tiles,
// K-step 64.  grid (8, 16), 256 thr.
// ---------------------------------------------------------------------------
__global__ __launch_bounds__(256) void k_out_mfma(
    const unsigned short* __restrict__ ub, const unsigned short* __restrict__ woT,
    const float* __restrict__ bo, float* __restrict__ out)
{
    const int tid = threadIdx.x;
    const int lane = tid & 63, wave = tid >> 6;
    const int q = lane >> 4, ln = lane & 15;
    const int wm = wave * 32;
    const int m0 = blockIdx.y * 128;
    const int n0 = blockIdx.x * 64;

    __shared__ unsigned short As[128*72];
    __shared__ unsigned short Bs[64*72];

    floatx4 acc[2][4];
    #pragma unroll
    for (int i = 0; i < 2; ++i)
        #pragma unroll
        for (int j = 0; j < 4; ++j)
            acc[i][j] = (floatx4){0.f, 0.f, 0.f, 0.f};

    const uint4* Ag = (const uint4*)ub;
    const uint4* Bg = (const uint4*)woT;
    for (int k0 = 0; k0 < 512; k0 += 64) {
        #pragma unroll
        for (int s = 0; s < 4; ++s) {
            int idx = s*256 + tid;
            int r = idx >> 3, cp = idx & 7;
            uint4 va = Ag[(size_t)(m0 + r)*64 + (k0 >> 3) + cp];
            *(uint4*)&As[r*72 + cp*8] = va;
        }
        #pragma unroll
        for (int s = 0; s < 2; ++s) {
            int idx = s*256 + tid;
            int r = idx >> 3, cp = idx & 7;
            uint4 vb = Bg[(size_t)(n0 + r)*64 + (k0 >> 3) + cp];
            *(uint4*)&Bs[r*72 + cp*8] = vb;
        }
        __syncthreads();
        short8 af0[2], af1[2], bf0[4], bf1[4];
        #pragma unroll
        for (int i = 0; i < 2; ++i) {
            af0[i] = *(const short8*)&As[(wm + i*16 + ln)*72 + q*8];
            af1[i] = *(const short8*)&As[(wm + i*16 + ln)*72 + 32 + q*8];
        }
        #pragma unroll
        for (int i = 0; i < 4; ++i) {
            bf0[i] = *(const short8*)&Bs[(i*16 + ln)*72 + q*8];
            bf1[i] = *(const short8*)&Bs[(i*16 + ln)*72 + 32 + q*8];
        }
        #pragma unroll
        for (int mi = 0; mi < 2; ++mi)
            #pragma unroll
            for (int ni = 0; ni < 4; ++ni) {
                acc[mi][ni] = __builtin_amdgcn_mfma_f32_16x16x32_bf16(
                    af0[mi], bf0[ni], acc[mi][ni], 0, 0, 0);
                acc[mi][ni] = __builtin_amdgcn_mfma_f32_16x16x32_bf16(
                    af1[mi], bf1[ni], acc[mi][ni], 0, 0, 0);
            }
        __syncthreads();
    }

    #pragma unroll
    for (int mi = 0; mi < 2; ++mi) {
        #pragma unroll
        for (int ni = 0; ni < 4; ++ni) {
            int gcol = n0 + ni*16 + ln;
            float bb = bo[gcol];
            #pragma unroll
            for (int reg = 0; reg < 4; ++reg) {
                int row = m0 + wm + mi*16 + q*4 + reg;
                out[(size_t)row*512 + gcol] = acc[mi][ni][reg] + bb;
            }
        }
    }
}

extern "C" void kernel_launch(void* const* d_in, const int* in_sizes, int n_in,
                              void* d_out, int out_size, void* d_ws, size_t ws_size,
                              hipStream_t stream)
{
    const float* x   = (const float*)d_in[0];
    const float* sb  = (const float*)d_in[1];
    const float* wq  = (const float*)d_in[2];
    const float* bq  = (const float*)d_in[3];
    const float* wk  = (const float*)d_in[4];
    const float* bk  = (const float*)d_in[5];
    const float* wv  = (const float*)d_in[6];
    const float* bv  = (const float*)d_in[7];
    const float* wo  = (const float*)d_in[8];
    const float* bo  = (const float*)d_in[9];
    const float* wg  = (const float*)d_in[10];
    const float* wgb = (const float*)d_in[11];
    float* out = (float*)d_out;
    float* ws  = (float*)d_ws;

    // workspace layout (float offsets)
    float* Q   = ws;                        // 1048576  [B,H,L,64] fp32
    float* KC  = ws + 1048576;              // 1048576  k_conv fp32
    float* VC  = ws + 2*1048576;            // 1048576  v_conv fp32
    float* GL  = ws + 3*1048576;            // 16384
    float* AP  = GL + 16384;                // 8*65536 = 524288
    float* fp  = AP + 524288;
    unsigned short* XB  = (unsigned short*)fp;              // 2048*512 bf16
    unsigned short* WT  = XB  + 1048576;                    // 1536*512 bf16
    unsigned short* WOT = WT  + 786432;                     // 512*512 bf16
    unsigned short* UB  = WOT + 262144;                     // 2048*512 bf16
    unsigned short* UB2 = UB  + 1048576;                    // 2*16*64*1024 bf16
    unsigned short* TB  = UB2 + 2097152;                    // 8*1024*1024 bf16
    unsigned short* WGB = TB  + 8388608;                    // 4096 bf16
    unsigned short* KCB = WGB + 4096;                       // 16*1024*64 bf16

    k_prep     <<<dim3(1025),   256, 0, stream>>>(x, wq, wk, wv, wo, sb, wg,
                                                  XB, WT, WOT, TB, WGB);
    k_qkv_mfma <<<dim3(24, 16), 256, 0, stream>>>(XB, WT, bq, bk, bv, Q, UB2);
    k_conv_mfma<<<dim3(32, 16), 256, 0, stream>>>(TB, UB2, KC, VC, KCB);
    k_gate_mfma<<<dim3(16, 16), 256, 0, stream>>>(KCB, VC, WGB, wgb, GL);
    k_amat     <<<dim3(16, 8),  256, 0, stream>>>(KC, VC, GL, AP);
    k_ctxt     <<<dim3(16, 16), 256, 0, stream>>>(Q, AP, UB);
    k_out_mfma <<<dim3(8, 16),  256, 0, stream>>>(UB, WOT, bo, out);
}

// Round 13
// 148.281 us; speedup vs baseline: 1.1827x; 1.0265x over previous
//
#include <hip/hip_runtime.h>
#include <math.h>

// Problem constants: B=2, L=1024, D=512, H=8, h=64, K=H=8, EPS=1e-5
// Layouts: q/kc/vc stored as [B*H][L][64] (bh*65536 + l*64 + d)
// UB2: bf16 conv inputs, d-major [tensor][bh][d=64][l=1024]
// KCB: bf16 k_conv, l-major [bh][l][64] (gate MFMA A-operand)
// Conv filter: built per-block in LDS as revf[i] = filt(1087-i) (zero-padded);
// A-fragment gather from revf replaces the old materialized Toeplitz tensor.

typedef __attribute__((ext_vector_type(8))) short short8;
typedef __attribute__((ext_vector_type(4))) float floatx4;

__device__ __forceinline__ unsigned short f2bf(float f) {
    unsigned int u = __float_as_uint(f);
    unsigned int r = (u + 0x7FFFu + ((u >> 16) & 1u)) >> 16;   // RNE
    return (unsigned short)r;
}

// ---------------------------------------------------------------------------
// K0: fused prep.  blocks 0-511: cast x -> bf16.  512-767: transpose+cast
// weights.  768: cast wg -> bf16.
// ---------------------------------------------------------------------------
__global__ __launch_bounds__(256) void k_prep(
    const float* __restrict__ x,
    const float* __restrict__ wq, const float* __restrict__ wk,
    const float* __restrict__ wv, const float* __restrict__ wo,
    const float* __restrict__ wg,
    unsigned short* __restrict__ xb,
    unsigned short* __restrict__ wT, unsigned short* __restrict__ woT,
    unsigned short* __restrict__ wgb)
{
    __shared__ float sf[64][65];
    const int blk = blockIdx.x;
    const int tid = threadIdx.x;

    if (blk < 512) {                       // ---- castx ----
        const int gid = blk * 256 + tid;
        const float4* x4 = (const float4*)x;
        float4 a = x4[gid*2], b = x4[gid*2+1];
        uint4 o;
        o.x = f2bf(a.x) | ((unsigned)f2bf(a.y) << 16);
        o.y = f2bf(a.z) | ((unsigned)f2bf(a.w) << 16);
        o.z = f2bf(b.x) | ((unsigned)f2bf(b.y) << 16);
        o.w = f2bf(b.z) | ((unsigned)f2bf(b.w) << 16);
        ((uint4*)xb)[gid] = o;
    } else if (blk < 768) {                // ---- packw ----
        const int t = blk - 512;
        const float* src; unsigned short* dst; int n0, c0, k0;
        if (t < 192) {
            int nt = t >> 3, kt = t & 7;
            n0 = nt * 64; k0 = kt * 64;
            int z = n0 >> 9; c0 = n0 & 511;
            src = (z == 0) ? wq : (z == 1) ? wk : wv;
            dst = wT;
        } else {
            int u = t - 192; int nt = u >> 3, kt = u & 7;
            n0 = nt * 64; c0 = n0; k0 = kt * 64;
            src = wo; dst = woT;
        }
        const int rr = tid >> 4, c4 = tid & 15;
        #pragma unroll
        for (int g = 0; g < 4; ++g) {
            int r = g*16 + rr;
            float4 v = *(const float4*)&src[(size_t)(k0 + r)*512 + c0 + c4*4];
            sf[r][c4*4+0]=v.x; sf[r][c4*4+1]=v.y; sf[r][c4*4+2]=v.z; sf[r][c4*4+3]=v.w;
        }
        __syncthreads();
        #pragma unroll
        for (int g = 0; g < 4; ++g) {
            int c = g*16 + rr;
            int kk = c4*4;
            ushort4 o;
            o.x = f2bf(sf[kk+0][c]); o.y = f2bf(sf[kk+1][c]);
            o.z = f2bf(sf[kk+2][c]); o.w = f2bf(sf[kk+3][c]);
            *(ushort4*)&dst[(size_t)(n0 + c)*512 + k0 + kk] = o;
        }
    } else {                               // ---- cast wg (4096 floats) ----
        const float4* wg4 = (const float4*)wg;
        for (int i = tid; i < 512; i += 256) {
            float4 a = wg4[i*2], b = wg4[i*2+1];
            uint4 o;
            o.x = f2bf(a.x) | ((unsigned)f2bf(a.y) << 16);
            o.y = f2bf(a.z) | ((unsigned)f2bf(a.w) << 16);
            o.z = f2bf(b.x) | ((unsigned)f2bf(b.y) << 16);
            o.w = f2bf(b.z) | ((unsigned)f2bf(b.w) << 16);
            ((uint4*)wgb)[i] = o;
        }
    }
}

// ---------------------------------------------------------------------------
// K1: QKV projection via MFMA, 128x64 tiles, K-step 64 (2 chunks/barrier).
// grid (24, 16), 256 thr.
// ---------------------------------------------------------------------------
__global__ __launch_bounds__(256) void k_qkv_mfma(
    const unsigned short* __restrict__ xb, const unsigned short* __restrict__ wT,
    const float* __restrict__ bq, const float* __restrict__ bk,
    const float* __restrict__ bv,
    float* __restrict__ qo, unsigned short* __restrict__ ub2)
{
    const int tid = threadIdx.x;
    const int lane = tid & 63, wave = tid >> 6;
    const int q = lane >> 4, ln = lane & 15;
    const int wm = wave * 32;
    const int m0 = blockIdx.y * 128;
    const int n0 = blockIdx.x * 64;

    __shared__ unsigned short As[128*72];   // 128 rows x 64 k (+8 pad)
    __shared__ unsigned short Bs[64*72];

    floatx4 acc[2][4];
    #pragma unroll
    for (int i = 0; i < 2; ++i)
        #pragma unroll
        for (int j = 0; j < 4; ++j)
            acc[i][j] = (floatx4){0.f, 0.f, 0.f, 0.f};

    const uint4* Ag = (const uint4*)xb;
    const uint4* Bg = (const uint4*)wT;
    for (int k0 = 0; k0 < 512; k0 += 64) {
        #pragma unroll
        for (int s = 0; s < 4; ++s) {
            int idx = s*256 + tid;
            int r = idx >> 3, cp = idx & 7;
            uint4 va = Ag[(size_t)(m0 + r)*64 + (k0 >> 3) + cp];
            *(uint4*)&As[r*72 + cp*8] = va;
        }
        #pragma unroll
        for (int s = 0; s < 2; ++s) {
            int idx = s*256 + tid;
            int r = idx >> 3, cp = idx & 7;
            uint4 vb = Bg[(size_t)(n0 + r)*64 + (k0 >> 3) + cp];
            *(uint4*)&Bs[r*72 + cp*8] = vb;
        }
        __syncthreads();
        short8 af0[2], af1[2], bf0[4], bf1[4];
        #pragma unroll
        for (int i = 0; i < 2; ++i) {
            af0[i] = *(const short8*)&As[(wm + i*16 + ln)*72 + q*8];
            af1[i] = *(const short8*)&As[(wm + i*16 + ln)*72 + 32 + q*8];
        }
        #pragma unroll
        for (int i = 0; i < 4; ++i) {
            bf0[i] = *(const short8*)&Bs[(i*16 + ln)*72 + q*8];
            bf1[i] = *(const short8*)&Bs[(i*16 + ln)*72 + 32 + q*8];
        }
        #pragma unroll
        for (int mi = 0; mi < 2; ++mi)
            #pragma unroll
            for (int ni = 0; ni < 4; ++ni) {
                acc[mi][ni] = __builtin_amdgcn_mfma_f32_16x16x32_bf16(
                    af0[mi], bf0[ni], acc[mi][ni], 0, 0, 0);
                acc[mi][ni] = __builtin_amdgcn_mfma_f32_16x16x32_bf16(
                    af1[mi], bf1[ni], acc[mi][ni], 0, 0, 0);
            }
        __syncthreads();
    }

    const int z = n0 >> 9;                 // 64-col block never straddles
    if (z == 0) {
        #pragma unroll
        for (int mi = 0; mi < 2; ++mi) {
            #pragma unroll
            for (int ni = 0; ni < 4; ++ni) {
                int c = (n0 + ni*16 + ln) & 511;
                int head = c >> 6, dd = c & 63;
                float bb = bq[c];
                #pragma unroll
                for (int reg = 0; reg < 4; ++reg) {
                    int row = m0 + wm + mi*16 + q*4 + reg;
                    int b = row >> 10, l = row & 1023;
                    qo[(size_t)((b*8 + head)*1024 + l)*64 + dd] =
                        acc[mi][ni][reg] + bb;
                }
            }
        }
    } else {
        const float scale = (z == 1) ? 0.125f : 1.0f;
        const float* bias = (z == 1) ? bk : bv;
        unsigned short* dst = ub2 + (size_t)(z-1) * 16 * 64 * 1024;
        #pragma unroll
        for (int mi = 0; mi < 2; ++mi) {
            #pragma unroll
            for (int ni = 0; ni < 4; ++ni) {
                int c = (n0 + ni*16 + ln) & 511;
                int head = c >> 6, dd = c & 63;
                float bb = bias[c];
                int row0 = m0 + wm + mi*16 + q*4;
                int b = row0 >> 10, l0 = row0 & 1023;
                ushort4 o;
                o.x = f2bf((acc[mi][ni][0] + bb) * scale);
                o.y = f2bf((acc[mi][ni][1] + bb) * scale);
                o.z = f2bf((acc[mi][ni][2] + bb) * scale);
                o.w = f2bf((acc[mi][ni][3] + bb) * scale);
                *(ushort4*)&dst[((size_t)((b*8 + head)*64) + dd)*1024 + l0] = o;
            }
        }
    }
}

// ---------------------------------------------------------------------------
// K2: conv as Toeplitz GEMM; A-fragments gathered from a per-block reversed
// filter table in LDS (revf) -- no materialized Toeplitz tensor, zero global
// A-traffic.  B staged coalesced -> ds_read_b128, K-step 64.
// grid (32 bht, 16 it), 256 thr.  k-tensor blocks also write KCB (bf16).
// A values identical to the old TB path -> bit-identical output.
// ---------------------------------------------------------------------------
__global__ __launch_bounds__(256) void k_conv_mfma(
    const float* __restrict__ sb,
    const unsigned short* __restrict__ ub2,
    float* __restrict__ kc, float* __restrict__ vc,
    unsigned short* __restrict__ kcb)
{
    const int tid = threadIdx.x;
    const int lane = tid & 63, wave = tid >> 6;
    const int q = lane >> 4, ln = lane & 15;
    const int bht = blockIdx.x;
    const int it  = blockIdx.y;
    const int t0  = it * 64;
    const int bh  = bht & 15, h = bh & 7, tensor = bht >> 4;

    __shared__ unsigned short revf[1152];  // revf[i] = filt(1087-i), 0-padded
    __shared__ unsigned short Bs[64*72];

    for (int i = tid; i < 1152; i += 256) {
        int d = 1087 - i;
        revf[i] = (d >= 0 && d < 1024) ? f2bf(sb[d*8 + h]) : (unsigned short)0;
    }

    const uint4* Bg = (const uint4*)ub2;
    const size_t bbase = (size_t)bht * 8192;

    floatx4 acc[4];
    #pragma unroll
    for (int i = 0; i < 4; ++i) acc[i] = (floatx4){0.f,0.f,0.f,0.f};

    const int kend = t0 + 64;
    const int arow = 1087 - t0 - (wave*16 + ln);   // + k0 + q*8 -> frag base
    for (int k0 = 0; k0 < kend; k0 += 64) {
        #pragma unroll
        for (int s = 0; s < 2; ++s) {
            int idx = s*256 + tid;
            int r = idx >> 3, cp = idx & 7;
            uint4 vb = Bg[bbase + (size_t)r*128 + (k0 >> 3) + cp];
            *(uint4*)&Bs[r*72 + cp*8] = vb;
        }
        __syncthreads();                   // also covers revf on first iter
        const int ab = arow + k0 + q*8;
        short8 a0, a1;
        #pragma unroll
        for (int j = 0; j < 8; ++j) {
            a0[j] = (short)revf[ab + j];
            a1[j] = (short)revf[ab + 32 + j];
        }
        #pragma unroll
        for (int ni = 0; ni < 4; ++ni) {
            short8 b0 = *(const short8*)&Bs[(ni*16 + ln)*72 + q*8];
            short8 b1 = *(const short8*)&Bs[(ni*16 + ln)*72 + 32 + q*8];
            acc[ni] = __builtin_amdgcn_mfma_f32_16x16x32_bf16(a0, b0, acc[ni], 0, 0, 0);
            acc[ni] = __builtin_amdgcn_mfma_f32_16x16x32_bf16(a1, b1, acc[ni], 0, 0, 0);
        }
        __syncthreads();
    }

    float* dst = (tensor ? vc : kc) + (size_t)bh * 65536;
    #pragma unroll
    for (int ni = 0; ni < 4; ++ni)
        #pragma unroll
        for (int reg = 0; reg < 4; ++reg) {
            int row = t0 + wave*16 + q*4 + reg;
            dst[(size_t)row*64 + ni*16 + ln] = acc[ni][reg];
        }
    if (!tensor) {
        unsigned short* db = kcb + (size_t)bh * 65536;
        #pragma unroll
        for (int ni = 0; ni < 4; ++ni)
            #pragma unroll
            for (int reg = 0; reg < 4; ++reg) {
                int row = t0 + wave*16 + q*4 + reg;
                db[(size_t)row*64 + ni*16 + ln] = f2bf(acc[ni][reg]);
            }
    }
}

// ---------------------------------------------------------------------------
// K3: gate via MFMA.  T = KCb @ Wgb^T (K=64, one-shot LDS stage), then
// logit[l] = sum_m V[l][m]*T[l][m] (shuffle rowsum), g = relu^2 + eps.
// grid (16 lTiles, 16 bh), 256 thr = 4 waves.
// ---------------------------------------------------------------------------
__global__ __launch_bounds__(256) void k_gate_mfma(
    const unsigned short* __restrict__ kcb, const float* __restrict__ vc,
    const unsigned short* __restrict__ wgb, const float* __restrict__ wg_b,
    float* __restrict__ gl)
{
    const int tid = threadIdx.x;
    const int lane = tid & 63, wave = tid >> 6;
    const int q = lane >> 4, ln = lane & 15;
    const int l0 = blockIdx.x * 64;
    const int bh = blockIdx.y;

    __shared__ unsigned short As[64*72];   // stride 72: 2-way banks (free)
    __shared__ unsigned short Bs[64*72];

    const uint4* Ag = (const uint4*)(kcb + (size_t)bh * 65536);
    const uint4* Bg = (const uint4*)wgb;
    #pragma unroll
    for (int s = 0; s < 2; ++s) {
        int idx = s*256 + tid;
        int r = idx >> 3, cp = idx & 7;
        *(uint4*)&As[r*72 + cp*8] = Ag[(size_t)(l0 + r)*8 + cp];
        *(uint4*)&Bs[r*72 + cp*8] = Bg[r*8 + cp];
    }
    __syncthreads();

    floatx4 T[4];
    #pragma unroll
    for (int mt = 0; mt < 4; ++mt) T[mt] = (floatx4){0.f,0.f,0.f,0.f};
    #pragma unroll
    for (int k0 = 0; k0 < 64; k0 += 32) {
        short8 a = *(const short8*)&As[(wave*16 + ln)*72 + k0 + q*8];
        #pragma unroll
        for (int mt = 0; mt < 4; ++mt) {
            short8 b = *(const short8*)&Bs[(mt*16 + ln)*72 + k0 + q*8];
            T[mt] = __builtin_amdgcn_mfma_f32_16x16x32_bf16(a, b, T[mt], 0, 0, 0);
        }
    }

    // rowsum of V .* T   (lane holds cols m = mt*16+ln, rows l = wave*16+q*4+reg)
    const float* vb = vc + (size_t)bh * 65536;
    float part[4] = {0.f, 0.f, 0.f, 0.f};
    #pragma unroll
    for (int mt = 0; mt < 4; ++mt)
        #pragma unroll
        for (int reg = 0; reg < 4; ++reg) {
            int l = l0 + wave*16 + q*4 + reg;
            part[reg] += T[mt][reg] * vb[(size_t)l*64 + mt*16 + ln];
        }
    #pragma unroll
    for (int reg = 0; reg < 4; ++reg) {
        part[reg] += __shfl_xor(part[reg], 1);
        part[reg] += __shfl_xor(part[reg], 2);
        part[reg] += __shfl_xor(part[reg], 4);
        part[reg] += __shfl_xor(part[reg], 8);
    }
    if (ln == 0) {
        const float wgbias = wg_b[0];
        #pragma unroll
        for (int reg = 0; reg < 4; ++reg) {
            int l = l0 + wave*16 + q*4 + reg;
            float s = part[reg] + wgbias;
            float rr = fmaxf(s, 0.0f);
            gl[bh*1024 + l] = rr*rr + 1e-5f;
        }
    }
}

// ---------------------------------------------------------------------------
// K4: A_part[slc][bh] = sum_{j in slice} w_j * outer(v_conv[j], k_conv[j]),
// gate scan inline.  grid (16 bh, 8 slices of 128), 256 thr.
// ---------------------------------------------------------------------------
__global__ __launch_bounds__(256) void k_amat(
    const float* __restrict__ kc, const float* __restrict__ vc,
    const float* __restrict__ gl, float* __restrict__ apart)
{
    const int tid = threadIdx.x, tx = tid & 15, ty = tid >> 4;
    const int bh = blockIdx.x, slc = blockIdx.y;
    const float* kb = kc + (size_t)bh * 65536;
    const float* vb = vc + (size_t)bh * 65536;

    __shared__ float sbuf[256];
    __shared__ float wfull[1024];
    __shared__ __align__(16) float vs[16][68];
    __shared__ __align__(16) float ks2[16][68];

    {
        const float4 g4 = ((const float4*)(gl + bh*1024))[tid];
        float g[4] = {g4.x, g4.y, g4.z, g4.w};
        float p[4];
        p[0]=g[0]; p[1]=p[0]+g[1]; p[2]=p[1]+g[2]; p[3]=p[2]+g[3];
        const float s = p[3];
        sbuf[tid] = s;
        __syncthreads();
        for (int off = 1; off < 256; off <<= 1) {
            float t = (tid >= off) ? sbuf[tid-off] : 0.0f;
            __syncthreads();
            sbuf[tid] += t;
            __syncthreads();
        }
        const float base = sbuf[tid] - s;
        float r[4], pr[4];
        #pragma unroll
        for (int u = 0; u < 4; ++u) r[u] = 1.0f / (base + p[u] + 1e-5f);
        pr[0]=r[0]; pr[1]=pr[0]+r[1]; pr[2]=pr[1]+r[2]; pr[3]=pr[2]+r[3];
        const float sr = pr[3];
        __syncthreads();
        sbuf[tid] = sr;
        __syncthreads();
        for (int off = 1; off < 256; off <<= 1) {
            float t = (tid >= off) ? sbuf[tid-off] : 0.0f;
            __syncthreads();
            sbuf[tid] += t;
            __syncthreads();
        }
        const float Rtot  = sbuf[255];
        const float baser = sbuf[tid] - sr;
        wfull[tid*4+0] = g[0] * (Rtot - (baser + pr[0]) + r[0]);
        wfull[tid*4+1] = g[1] * (Rtot - (baser + pr[1]) + r[1]);
        wfull[tid*4+2] = g[2] * (Rtot - (baser + pr[2]) + r[2]);
        wfull[tid*4+3] = g[3] * (Rtot - (baser + pr[3]) + r[3]);
    }
    __syncthreads();

    float acc[4][4] = {};
    const float4* k4 = (const float4*)kb;
    const float4* v4 = (const float4*)vb;
    for (int j0 = slc*128; j0 < slc*128 + 128; j0 += 16) {
        {
            int r = tid >> 4, c4 = tid & 15;
            *(float4*)&vs[r][c4*4]  = v4[(size_t)(j0 + r)*16 + c4];
            *(float4*)&ks2[r][c4*4] = k4[(size_t)(j0 + r)*16 + c4];
        }
        __syncthreads();
        #pragma unroll
        for (int jj = 0; jj < 16; ++jj) {
            float wj = wfull[j0 + jj];
            float a[4];
            a[0] = vs[jj][ty*4+0]*wj; a[1] = vs[jj][ty*4+1]*wj;
            a[2] = vs[jj][ty*4+2]*wj; a[3] = vs[jj][ty*4+3]*wj;
            float4 b4 = *(const float4*)&ks2[jj][tx*4];
            float bb[4] = {b4.x, b4.y, b4.z, b4.w};
            #pragma unroll
            for (int ii = 0; ii < 4; ++ii)
                #pragma unroll
                for (int jc = 0; jc < 4; ++jc)
                    acc[ii][jc] += a[ii] * bb[jc];
        }
        __syncthreads();
    }
    float* ap = apart + (size_t)(slc*16 + bh) * 4096;
    #pragma unroll
    for (int i = 0; i < 4; ++i) {
        float4 o = { acc[i][0], acc[i][1], acc[i][2], acc[i][3] };
        *(float4*)&ap[(ty*4+i)*64 + tx*4] = o;
    }
}

// ---------------------------------------------------------------------------
// K5: ctxt = q @ A (summing the 8 A-partials on load), row-normalize,
// write unit vectors as bf16 into [B,L,D] layout.  grid (16, 16), 256 thr.
// ---------------------------------------------------------------------------
__global__ __launch_bounds__(256) void k_ctxt(
    const float* __restrict__ q, const float* __restrict__ apart,
    unsigned short* __restrict__ ub)
{
    const int tid = threadIdx.x, tx = tid & 15, ty = tid >> 4;
    const int l0 = blockIdx.x * 64;
    const int bh = blockIdx.y;
    const float* qb = q + (size_t)bh * 65536;

    __shared__ __align__(16) float qs[64][20];
    __shared__ __align__(16) float As[16][68];
    float acc[4][4] = {};
    const float4* q4 = (const float4*)qb;
    const float4* a4 = (const float4*)apart;
    for (int d0 = 0; d0 < 64; d0 += 16) {
        {
            int r = tid >> 2, c4 = tid & 3;
            float4 t = q4[(size_t)(l0 + r)*16 + (d0 >> 2) + c4];
            *(float4*)&qs[r][c4*4] = t;
        }
        {
            int r = tid >> 4, c4 = tid & 15;
            size_t o = (size_t)(d0 + r)*16 + c4;
            float4 t = a4[(size_t)(0*16 + bh)*1024 + o];
            #pragma unroll
            for (int s = 1; s < 8; ++s) {
                float4 u = a4[(size_t)(s*16 + bh)*1024 + o];
                t.x += u.x; t.y += u.y; t.z += u.z; t.w += u.w;
            }
            *(float4*)&As[r][c4*4] = t;
        }
        __syncthreads();
        float qreg[4][16];
        #pragma unroll
        for (int i = 0; i < 4; ++i)
            #pragma unroll
            for (int c = 0; c < 4; ++c) {
                float4 t = *(const float4*)&qs[ty*4+i][c*4];
                qreg[i][c*4+0] = t.x; qreg[i][c*4+1] = t.y;
                qreg[i][c*4+2] = t.z; qreg[i][c*4+3] = t.w;
            }
        #pragma unroll
        for (int dd = 0; dd < 16; ++dd) {
            float4 b4 = *(const float4*)&As[dd][tx*4];
            float bb[4] = {b4.x, b4.y, b4.z, b4.w};
            #pragma unroll
            for (int ii = 0; ii < 4; ++ii)
                #pragma unroll
                for (int jj = 0; jj < 4; ++jj)
                    acc[ii][jj] += qreg[ii][dd] * bb[jj];
        }
        __syncthreads();
    }
    __shared__ float red[64][17];
    __shared__ float nrm[64];
    #pragma unroll
    for (int i = 0; i < 4; ++i) {
        red[ty*4+i][tx] = acc[i][0]*acc[i][0] + acc[i][1]*acc[i][1]
                        + acc[i][2]*acc[i][2] + acc[i][3]*acc[i][3];
    }
    __syncthreads();
    if (tid < 64) {
        float s = 0.0f;
        #pragma unroll
        for (int t = 0; t < 16; ++t) s += red[tid][t];
        nrm[tid] = fmaxf(sqrtf(s), 1e-5f);
    }
    __syncthreads();
    const int b = bh >> 3, hd = bh & 7;
    #pragma unroll
    for (int i = 0; i < 4; ++i) {
        int lr = ty*4 + i;
        float inv = 1.0f / nrm[lr];
        ushort4 o;
        o.x = f2bf(acc[i][0]*inv); o.y = f2bf(acc[i][1]*inv);
        o.z = f2bf(acc[i][2]*inv); o.w = f2bf(acc[i][3]*inv);
        *(ushort4*)&ub[(size_t)(b*1024 + l0 + lr)*512 + hd*64 + tx*4] = o;
    }
}

// ---------------------------------------------------------------------------
// K6: out = Ub[2048][512](bf16) @ woT^T + wo_b via MFMA, 128x64 tiles,
// K-step 64.  grid (8, 16), 256 thr.
// ---------------------------------------------------------------------------
__global__ __launch_bounds__(256) void k_out_mfma(
    const unsigned short* __restrict__ ub, const unsigned short* __restrict__ woT,
    const float* __restrict__ bo, float* __restrict__ out)
{
    const int tid = threadIdx.x;
    const int lane = tid & 63, wave = tid >> 6;
    const int q = lane >> 4, ln = lane & 15;
    const int wm = wave * 32;
    const int m0 = blockIdx.y * 128;
    const int n0 = blockIdx.x * 64;

    __shared__ unsigned short As[128*72];
    __shared__ unsigned short Bs[64*72];

    floatx4 acc[2][4];
    #pragma unroll
    for (int i = 0; i < 2; ++i)
        #pragma unroll
        for (int j = 0; j < 4; ++j)
            acc[i][j] = (floatx4){0.f, 0.f, 0.f, 0.f};

    const uint4* Ag = (const uint4*)ub;
    const uint4* Bg = (const uint4*)woT;
    for (int k0 = 0; k0 < 512; k0 += 64) {
        #pragma unroll
        for (int s = 0; s < 4; ++s) {
            int idx = s*256 + tid;
            int r = idx >> 3, cp = idx & 7;
            uint4 va = Ag[(size_t)(m0 + r)*64 + (k0 >> 3) + cp];
            *(uint4*)&As[r*72 + cp*8] = va;
        }
        #pragma unroll
        for (int s = 0; s < 2; ++s) {
            int idx = s*256 + tid;
            int r = idx >> 3, cp = idx & 7;
            uint4 vb = Bg[(size_t)(n0 + r)*64 + (k0 >> 3) + cp];
            *(uint4*)&Bs[r*72 + cp*8] = vb;
        }
        __syncthreads();
        short8 af0[2], af1[2], bf0[4], bf1[4];
        #pragma unroll
        for (int i = 0; i < 2; ++i) {
            af0[i] = *(const short8*)&As[(wm + i*16 + ln)*72 + q*8];
            af1[i] = *(const short8*)&As[(wm + i*16 + ln)*72 + 32 + q*8];
        }
        #pragma unroll
        for (int i = 0; i < 4; ++i) {
            bf0[i] = *(const short8*)&Bs[(i*16 + ln)*72 + q*8];
            bf1[i] = *(const short8*)&Bs[(i*16 + ln)*72 + 32 + q*8];
        }
        #pragma unroll
        for (int mi = 0; mi < 2; ++mi)
            #pragma unroll
            for (int ni = 0; ni < 4; ++ni) {
                acc[mi][ni] = __builtin_amdgcn_mfma_f32_16x16x32_bf16(
                    af0[mi], bf0[ni], acc[mi][ni], 0, 0, 0);
                acc[mi][ni] = __builtin_amdgcn_mfma_f32_16x16x32_bf16(
                    af1[mi], bf1[ni], acc[mi][ni], 0, 0, 0);
            }
        __syncthreads();
    }

    #pragma unroll
    for (int mi = 0; mi < 2; ++mi) {
        #pragma unroll
        for (int ni = 0; ni < 4; ++ni) {
            int gcol = n0 + ni*16 + ln;
            float bb = bo[gcol];
            #pragma unroll
            for (int reg = 0; reg < 4; ++reg) {
                int row = m0 + wm + mi*16 + q*4 + reg;
                out[(size_t)row*512 + gcol] = acc[mi][ni][reg] + bb;
            }
        }
    }
}

extern "C" void kernel_launch(void* const* d_in, const int* in_sizes, int n_in,
                              void* d_out, int out_size, void* d_ws, size_t ws_size,
                              hipStream_t stream)
{
    const float* x   = (const float*)d_in[0];
    const float* sb  = (const float*)d_in[1];
    const float* wq  = (const float*)d_in[2];
    const float* bq  = (const float*)d_in[3];
    const float* wk  = (const float*)d_in[4];
    const float* bk  = (const float*)d_in[5];
    const float* wv  = (const float*)d_in[6];
    const float* bv  = (const float*)d_in[7];
    const float* wo  = (const float*)d_in[8];
    const float* bo  = (const float*)d_in[9];
    const float* wg  = (const float*)d_in[10];
    const float* wgb = (const float*)d_in[11];
    float* out = (float*)d_out;
    float* ws  = (float*)d_ws;

    // workspace layout (float offsets)
    float* Q   = ws;                        // 1048576  [B,H,L,64] fp32
    float* KC  = ws + 1048576;              // 1048576  k_conv fp32
    float* VC  = ws + 2*1048576;            // 1048576  v_conv fp32
    float* GL  = ws + 3*1048576;            // 16384
    float* AP  = GL + 16384;                // 8*65536 = 524288
    float* fp  = AP + 524288;
    unsigned short* XB  = (unsigned short*)fp;              // 2048*512 bf16
    unsigned short* WT  = XB  + 1048576;                    // 1536*512 bf16
    unsigned short* WOT = WT  + 786432;                     // 512*512 bf16
    unsigned short* UB  = WOT + 262144;                     // 2048*512 bf16
    unsigned short* UB2 = UB  + 1048576;                    // 2*16*64*1024 bf16
    unsigned short* WGB = UB2 + 2097152;                    // 4096 bf16
    unsigned short* KCB = WGB + 4096;                       // 16*1024*64 bf16

    k_prep     <<<dim3(769),    256, 0, stream>>>(x, wq, wk, wv, wo, wg,
                                                  XB, WT, WOT, WGB);
    k_qkv_mfma <<<dim3(24, 16), 256, 0, stream>>>(XB, WT, bq, bk, bv, Q, UB2);
    k_conv_mfma<<<dim3(32, 16), 256, 0, stream>>>(sb, UB2, KC, VC, KCB);
    k_gate_mfma<<<dim3(16, 16), 256, 0, stream>>>(KCB, VC, WGB, wgb, GL);
    k_amat     <<<dim3(16, 8),  256, 0, stream>>>(KC, VC, GL, AP);
    k_ctxt     <<<dim3(16, 16), 256, 0, stream>>>(Q, AP, UB);
    k_out_mfma <<<dim3(8, 16),  256, 0, stream>>>(UB, WOT, bo, out);
}